// Round 5
// baseline (28122.934 us; speedup 1.0000x reference)
//
#include <hip/hip_runtime.h>
#include <cstddef>

#define DEV static __device__ __forceinline__
typedef unsigned long long ull;

DEV float b2f(unsigned short u){ unsigned int i=((unsigned int)u)<<16; float f; __builtin_memcpy(&f,&i,4); return f; }
DEV float lo16(unsigned int u){ unsigned int i=u<<16; float f; __builtin_memcpy(&f,&i,4); return f; }
DEV float hi16(unsigned int u){ unsigned int i=u&0xffff0000u; float f; __builtin_memcpy(&f,&i,4); return f; }
DEV unsigned short f2b(float f){ unsigned int i; __builtin_memcpy(&i,&f,4); unsigned int r=(i+0x7fffu+((i>>16)&1u))>>16; return (unsigned short)r; }
DEV float sigf(float x){ return 1.f/(1.f+__expf(-x)); }
DEV float eluf(float x){ return x>0.f ? x : (__expf(x)-1.f); }
DEV float gload(const void* p, long i, int f32){
  return f32 ? ((const float*)p)[i] : b2f(((const unsigned short*)p)[i]);
}
// tagged-word mailbox: {tag<<32 | f32 bits}, relaxed agent atomics (LLC point).
DEV ull pk(float f, unsigned tag){ unsigned b; __builtin_memcpy(&b,&f,4); return ((ull)tag<<32)|b; }
DEV float upk(ull u){ unsigned b=(unsigned)u; float f; __builtin_memcpy(&f,&b,4); return f; }
DEV void ast64(ull* p, ull v){ __hip_atomic_store(p, v, __ATOMIC_RELAXED, __HIP_MEMORY_SCOPE_AGENT); }
DEV ull ald64(const ull* p){ return __hip_atomic_load(p, __ATOMIC_RELAXED, __HIP_MEMORY_SCOPE_AGENT); }

// ---------------------------------------------------------------------------
// Sniff input dtypes. flags[0]=1 if floats are f32; flags[1]=1 if ints are i64.
// ---------------------------------------------------------------------------
__global__ __launch_bounds__(64) void sniff(const void* __restrict__ seqs,
                                            const void* __restrict__ seq_lens,
                                            int* __restrict__ flags)
{
  __shared__ int cnt;
  if (threadIdx.x==0) cnt=0;
  __syncthreads();
  const unsigned short* u = (const unsigned short*)seqs;
  int sane=0;
  for (int i=threadIdx.x;i<1024;i+=64){
    int e = (u[i]>>7)&0xFF;
    if (e>=0x70 && e<=0x8F) sane++;
  }
  atomicAdd(&cnt, sane);
  __syncthreads();
  if (threadIdx.x==0){
    flags[0] = (cnt < 820) ? 1 : 0;
    const int* s = (const int*)seq_lens;
    flags[1] = ((s[1]|s[3]|s[5]|s[7])==0) ? 1 : 0;
  }
}

// ---------------------------------------------------------------------------
// Prep: part-sliced bf16 weights, r5 lane-mapped layout.
// LSTM: lane ln in [0,512): j=ln>>3 (output), gi=(ln>>1)&3 (gate type),
// half=ln&1 (k-half). Wl[p][it8][ln][e]: element = W[g][k], g = gi*256+p*64+j,
// k = half*256 + it8*8 + e.  k<256 -> ih (ctx/h_in), k>=256 -> hh.
// qW0v[k8][ln][e]: j=ln>>1, half=ln&1, k = half*128 + k8*8 + e (k8<16).
// qW1v[g][ln][e]: qc=ln>>3, s8=ln&7, k = s8*32 + g*8 + e (g<4).
// ---------------------------------------------------------------------------
__global__ __launch_bounds__(256) void prep_transpose(
    const void* __restrict__ Wih0, const void* __restrict__ Whh0,
    const void* __restrict__ Wih1, const void* __restrict__ Whh1,
    const void* __restrict__ Wih2, const void* __restrict__ Whh2,
    const void* __restrict__ kW0,  const void* __restrict__ kW1,
    const void* __restrict__ vW0,  const void* __restrict__ vW1,
    const void* __restrict__ qW0,  const void* __restrict__ qW1,
    const void* __restrict__ bih0, const void* __restrict__ bhh0,
    const void* __restrict__ bih1, const void* __restrict__ bhh1,
    const void* __restrict__ bih2, const void* __restrict__ bhh2,
    const void* __restrict__ outW, const void* __restrict__ inith,
    const void* __restrict__ initc, const void* __restrict__ qb0,
    const void* __restrict__ qb1,  const void* __restrict__ outb,
    const int* __restrict__ flags,
    unsigned short* __restrict__ Wl0, unsigned short* __restrict__ Wl1,
    unsigned short* __restrict__ Wl2,
    unsigned short* __restrict__ kW0T, unsigned short* __restrict__ kW1T,
    unsigned short* __restrict__ vW0T, unsigned short* __restrict__ vW1T,
    unsigned short* __restrict__ qW0v, unsigned short* __restrict__ qW1v,
    float* __restrict__ bsum,
    unsigned short* __restrict__ outWc, unsigned short* __restrict__ inithc,
    unsigned short* __restrict__ initcc, unsigned short* __restrict__ qb0c,
    unsigned short* __restrict__ qb1c,  unsigned short* __restrict__ outbc)
{
  const int f32 = flags[0];
  int idx = blockIdx.x*256 + threadIdx.x;
  if (idx < 524288){ int pp=idx>>17, r=idx&131071;
    int it8=r>>12, ln=(r>>3)&511, e=r&7;
    int j=ln>>3, gi=(ln>>1)&3, half=ln&1;
    int g = gi*256 + pp*64 + j;
    int k = half*256 + it8*8 + e;
    Wl0[idx] = f2b((k<256)? gload(Wih0,(long)g*512+k,f32) : gload(Whh0,(long)g*256+(k-256),f32)); return; }
  idx -= 524288;
  if (idx < 524288){ int pp=idx>>17, r=idx&131071;
    int it8=r>>12, ln=(r>>3)&511, e=r&7;
    int j=ln>>3, gi=(ln>>1)&3, half=ln&1;
    int g = gi*256 + pp*64 + j;
    int k = half*256 + it8*8 + e;
    Wl1[idx] = f2b((k<256)? gload(Wih1,(long)g*256+k,f32) : gload(Whh1,(long)g*256+(k-256),f32)); return; }
  idx -= 524288;
  if (idx < 524288){ int pp=idx>>17, r=idx&131071;
    int it8=r>>12, ln=(r>>3)&511, e=r&7;
    int j=ln>>3, gi=(ln>>1)&3, half=ln&1;
    int g = gi*256 + pp*64 + j;
    int k = half*256 + it8*8 + e;
    Wl2[idx] = f2b((k<256)? gload(Wih2,(long)g*256+k,f32) : gload(Whh2,(long)g*256+(k-256),f32)); return; }
  idx -= 524288;
  if (idx < 262144){ int k=idx>>9, j=idx&511; kW0T[idx]=f2b(gload(kW0,(long)j*512+k,f32)); return; }
  idx -= 262144;
  if (idx < 32768){ int k=idx>>6, j=idx&63; kW1T[idx]=f2b(gload(kW1,(long)j*512+k,f32)); return; }
  idx -= 32768;
  if (idx < 131072){ int k=idx>>8, j=idx&255; vW0T[idx]=f2b(gload(vW0,(long)j*512+k,f32)); return; }
  idx -= 131072;
  if (idx < 65536){ int k=idx>>8, j=idx&255; vW1T[idx]=f2b(gload(vW1,(long)j*256+k,f32)); return; }
  idx -= 65536;
  if (idx < 65536){ // qW0v[(k8*512+ln)*8+e] = qW0[ln>>1][(ln&1)*128 + k8*8 + e]
    int k8=idx>>12, ln=(idx>>3)&511, e=idx&7;
    int j=ln>>1, half=ln&1; int k=half*128 + k8*8 + e;
    qW0v[idx]=f2b(gload(qW0,(long)j*256+k,f32)); return; }
  idx -= 65536;
  if (idx < 16384){ // qW1v[(g*512+ln)*8+e] = qW1[ln>>3][(ln&7)*32 + g*8 + e]
    int g=idx>>12, ln=(idx>>3)&511, e=idx&7;
    int qc=ln>>3, s8=ln&7; int k=s8*32 + g*8 + e;
    qW1v[idx]=f2b(gload(qW1,(long)qc*256+k,f32)); return; }
  idx -= 16384;
  if (idx < 3072){ int l=idx>>10, r=idx&1023, pp=r>>8, gi=r&255;
    int g = ((gi>>6)<<8) + (pp<<6) + (gi&63);
    const void* bi = (l==0)?bih0:((l==1)?bih1:bih2);
    const void* bh = (l==0)?bhh0:((l==1)?bhh1:bhh2);
    bsum[idx] = gload(bi,g,f32)+gload(bh,g,f32); return; }
  idx -= 3072;
  if (idx < 17408){ outWc[idx]=f2b(gload(outW,idx,f32)); return; }
  idx -= 17408;
  if (idx < 768){ inithc[idx]=f2b(gload(inith,idx,f32)); return; }
  idx -= 768;
  if (idx < 768){ initcc[idx]=f2b(gload(initc,idx,f32)); return; }
  idx -= 768;
  if (idx < 256){ qb0c[idx]=f2b(gload(qb0,idx,f32)); return; }
  idx -= 256;
  if (idx < 64){ qb1c[idx]=f2b(gload(qb1,idx,f32)); return; }
  idx -= 64;
  if (idx < 34){ outbc[idx]=f2b(gload(outb,idx,f32)); return; }
}

// gep[part][v][gi] = sum_k emb[v][k] * Wih0[g(part,gi)][256+k]
__global__ __launch_bounds__(256) void prep_ge(
    const void* __restrict__ emb,
    const void* __restrict__ Wih0,
    const int* __restrict__ flags,
    float* __restrict__ gep)
{
  __shared__ float ev[256];
  const int f32 = flags[0];
  const int v = blockIdx.x, tid = threadIdx.x;
  ev[tid] = gload(emb,(long)v*256+tid,f32);
  __syncthreads();
  #pragma unroll
  for (int j=0;j<4;j++){
    const int g = tid*4+j;
    float a = 0.f;
    #pragma unroll 4
    for (int k=0;k<256;k++) a += ev[k]*gload(Wih0,(long)g*512+256+k,f32);
    int pp = (g>>6)&3, gi = ((g>>8)<<6)|(g&63);
    gep[((size_t)pp*34+v)*256+gi] = a;
  }
}

// ---------------------------------------------------------------------------
// key MLP: keyT[n][q][l]  (unchanged)
// ---------------------------------------------------------------------------
__global__ __launch_bounds__(256) void key_mlp(
    const void* __restrict__ seqs,
    const unsigned short* __restrict__ kW0T, const void* __restrict__ kb0,
    const unsigned short* __restrict__ kW1T, const void* __restrict__ kb1,
    const int* __restrict__ flags,
    unsigned short* __restrict__ keyT)
{
  __shared__ float Xt[16*512];
  __shared__ unsigned short Hd[16*512];
  const int f32 = flags[0];
  const int tid = threadIdx.x;
  const int R0 = blockIdx.x*16;
  for (int i=tid;i<8192;i+=256) Xt[i] = gload(seqs,(long)R0*512+i,f32);
  __syncthreads();
  {
    const int j0 = 2*tid;
    float acc0[16], acc1[16];
    #pragma unroll
    for (int r=0;r<16;r++){ acc0[r]=0.f; acc1[r]=0.f; }
    for (int k=0;k<512;k++){
      ushort2 w = *reinterpret_cast<const ushort2*>(kW0T + (size_t)k*512 + j0);
      float w0=b2f(w.x), w1=b2f(w.y);
      #pragma unroll
      for (int r=0;r<16;r++){ float x = Xt[r*512+k]; acc0[r]+=x*w0; acc1[r]+=x*w1; }
    }
    float b0v=gload(kb0,j0,f32), b1v=gload(kb0,j0+1,f32);
    #pragma unroll
    for (int r=0;r<16;r++){
      Hd[r*512+j0]   = f2b(eluf(acc0[r]+b0v));
      Hd[r*512+j0+1] = f2b(eluf(acc1[r]+b1v));
    }
  }
  __syncthreads();
  {
    const int j = tid & 63;
    const int rbase = tid >> 6;
    float acc[4] = {0.f,0.f,0.f,0.f};
    for (int k=0;k<512;k++){
      float w = b2f(kW1T[(size_t)k*64 + j]);
      #pragma unroll
      for (int m=0;m<4;m++) acc[m] += b2f(Hd[(rbase+4*m)*512 + k]) * w;
    }
    float bv = gload(kb1,j,f32);
    #pragma unroll
    for (int m=0;m<4;m++){
      int R = R0 + rbase + 4*m;
      int l = R >> 6, n = R & 63;
      keyT[((size_t)(n*64 + j))*1024 + l] = f2b(acc[m]+bv);
    }
  }
}

// ---------------------------------------------------------------------------
// value MLP: value[n][l][h]  (unchanged)
// ---------------------------------------------------------------------------
__global__ __launch_bounds__(256) void value_mlp(
    const void* __restrict__ seqs,
    const unsigned short* __restrict__ vW0T, const void* __restrict__ vb0,
    const unsigned short* __restrict__ vW1T, const void* __restrict__ vb1,
    const int* __restrict__ flags,
    unsigned short* __restrict__ value)
{
  __shared__ float Xt[16*512];
  __shared__ float Hd[16*256];
  const int f32 = flags[0];
  const int tid = threadIdx.x;
  const int R0 = blockIdx.x*16;
  for (int i=tid;i<8192;i+=256) Xt[i] = gload(seqs,(long)R0*512+i,f32);
  __syncthreads();
  {
    const int j0 = 2*(tid & 127);
    const int rh = tid >> 7;
    float acc0[8], acc1[8];
    #pragma unroll
    for (int r=0;r<8;r++){ acc0[r]=0.f; acc1[r]=0.f; }
    for (int k=0;k<512;k++){
      ushort2 w = *reinterpret_cast<const ushort2*>(vW0T + (size_t)k*256 + j0);
      float w0=b2f(w.x), w1=b2f(w.y);
      #pragma unroll
      for (int r=0;r<8;r++){ float x = Xt[(rh*8+r)*512+k]; acc0[r]+=x*w0; acc1[r]+=x*w1; }
    }
    float b0v=gload(vb0,j0,f32), b1v=gload(vb0,j0+1,f32);
    #pragma unroll
    for (int r=0;r<8;r++){
      Hd[(rh*8+r)*256+j0]   = eluf(acc0[r]+b0v);
      Hd[(rh*8+r)*256+j0+1] = eluf(acc1[r]+b1v);
    }
  }
  __syncthreads();
  {
    const int j = tid;
    float acc[16];
    #pragma unroll
    for (int r=0;r<16;r++) acc[r]=0.f;
    for (int k=0;k<256;k++){
      float w = b2f(vW1T[(size_t)k*256 + j]);
      #pragma unroll
      for (int r=0;r<16;r++) acc[r] += Hd[r*256+k]*w;
    }
    float bv = gload(vb1,j,f32);
    #pragma unroll
    for (int r=0;r<16;r++){
      int R = R0 + r; int l = R>>6, n = R&63;
      value[((size_t)n*1024 + l)*256 + j] = f2b(acc[r]+bv);
    }
  }
}

__global__ __launch_bounds__(256) void zero_hbuf(ull* __restrict__ f){
  int i = blockIdx.x*256 + threadIdx.x;
  if (i < 115200) f[i] = 0;   // tag 0 matches no round (tags start at 1)
}

// ---------------------------------------------------------------------------
// Decode: 256 blocks x 512 threads, 1 block/CU. Block bid = n*4+p so XCD
// (bid%8) hosts a single part -> per-XCD L2 footprint ~2 MB. DO NOT remap
// (r1: FETCH x7, 3x slower). DO NOT widen blocks (r3: 2x slower).
// r4 evidence: polls find tags in ~1-2 iterations (FETCH near baseline) ->
// time is the block's OWN phase pipeline, not exchange latency.
// r5 structure: shfl-reduce LSTM (8 lanes per output j: 4 gates x 2 k-halves,
// one 256-MAC dot per thread, __shfl reduce, distributed act) — no sacc
// round-trip, no reduce phase, 2 thin barriers/round. Stage-B weights
// register-resident (32 uint4/thread, loaded once, reused 256 steps).
// Attn q-MLP shfl-ized the same way (2 fewer barriers, no sacc round-trip).
// Mailbox per n (ull): H0[256] H1[256] H2[256] PCTX[4][256] STAT[4][2].
// ---------------------------------------------------------------------------
__global__ __launch_bounds__(512, 1) void speller(
    const unsigned short* __restrict__ keyT,
    const unsigned short* __restrict__ value,
    const unsigned short* __restrict__ Wl0,
    const unsigned short* __restrict__ Wl1,
    const unsigned short* __restrict__ Wl2,
    const unsigned short* __restrict__ qW0v,
    const unsigned short* __restrict__ qW1v,
    const float* __restrict__ bsum_p,
    const float* __restrict__ gep,
    const unsigned short* __restrict__ inithc,
    const unsigned short* __restrict__ initcc,
    const unsigned short* __restrict__ qb0c,
    const unsigned short* __restrict__ qb1c,
    const unsigned short* __restrict__ outWc,
    const unsigned short* __restrict__ outbc,
    const int* __restrict__ labels,
    const int* __restrict__ seq_lens,
    const int* __restrict__ dflags,
    ull* __restrict__ hbw,
    void* __restrict__ out)
{
  extern __shared__ char smem_dyn[];
  unsigned short* vlds = (unsigned short*)smem_dyn;   // [256 l][256 h] quarter, 128 KB

  __shared__ float sacc[1024];
  __shared__ __align__(16) float xb[512];
  __shared__ float h0[256], h1[256], h2[256], ctx[256];
  __shared__ float cloc[3][64];
  __shared__ float hown[3][64];
  __shared__ float bsl[3][256];
  __shared__ float xq[256];
  __shared__ float qv[64];
  __shared__ float earr[256];
  __shared__ float red[16];
  __shared__ float wf[4];
  __shared__ float pcl[256];
  __shared__ float statl[8];

  const int tid = threadIdx.x;
  const int n = blockIdx.x >> 2;     // bid = n*4 + p
  const int p = blockIdx.x & 3;
  const int f32o = dflags[0];
  const int i64 = dflags[1];
  const int slen = i64 ? seq_lens[2*n] : seq_lens[n];

  ull* mb   = hbw + (size_t)n*1800;
  ull* H0w  = mb;            // [256]
  ull* H1w  = mb + 256;      // [256]
  ull* H2w  = mb + 512;      // [256]
  ull* PCw  = mb + 768;      // [4][256]
  ull* STw  = mb + 1792;     // [4][2]

  // preload value quarter into LDS (once)
  {
    const uint4* src = (const uint4*)(value + ((size_t)n*1024 + p*256)*256);
    uint4* dst = (uint4*)vlds;
    for (int i=tid;i<16384;i+=512) dst[i] = src[i];
  }
  if (tid < 256){ h0[tid]=b2f(inithc[tid]); h1[tid]=b2f(inithc[256+tid]); h2[tid]=b2f(inithc[512+tid]); }
  if (tid < 64){
    cloc[0][tid]=b2f(initcc[p*64+tid]);
    cloc[1][tid]=b2f(initcc[256+p*64+tid]);
    cloc[2][tid]=b2f(initcc[512+p*64+tid]);
  }
  for (int i=tid;i<768;i+=512){ int l=i>>8, gx=i&255; bsl[l][gx]=bsum_p[l*1024 + p*256 + gx]; }
  // stage-B weights into registers: 32 uint4 = 128 VGPR, reused 256 steps
  uint4 w1r[32];
  {
    const unsigned short* wp1 = Wl1 + (size_t)p*131072 + tid*8;
    #pragma unroll
    for (int i=0;i<32;i++) w1r[i] = *reinterpret_cast<const uint4*>(wp1 + (size_t)i*4096);
  }
  __syncthreads();

  const int half = tid & 1;
  const int gidx = ((tid>>1)&3)*64 + (tid>>3);   // gate-type*64 + j
  const int lb   = (tid & 63) & ~7;              // lane-group base within wave

  // LSTM with L2-streamed weights (stages A, C). x from xb[512] LDS.
  auto lstm_stream = [&](const unsigned short* W, int layer, const float* ger,
                         ull* Hw, unsigned tag){
    const float* xs = xb + half*256;
    const unsigned short* wp = W + (size_t)p*131072 + tid*8;
    float a = 0.f;
    #pragma unroll 8
    for (int it8=0; it8<32; it8++){
      uint4 w = *reinterpret_cast<const uint4*>(wp + (size_t)it8*4096);
      float4 x0 = *reinterpret_cast<const float4*>(xs + it8*8);
      float4 x1 = *reinterpret_cast<const float4*>(xs + it8*8 + 4);
      a += x0.x*lo16(w.x)+x0.y*hi16(w.x)+x0.z*lo16(w.y)+x0.w*hi16(w.y)
         + x1.x*lo16(w.z)+x1.y*hi16(w.z)+x1.z*lo16(w.w)+x1.w*hi16(w.w);
    }
    a += __shfl_xor(a, 1);
    float gsum = a + bsl[layer][gidx] + (ger ? ger[gidx] : 0.f);
    float g_i = __shfl(gsum, lb+0);
    float g_f = __shfl(gsum, lb+2);
    float g_g = __shfl(gsum, lb+4);
    float g_o = __shfl(gsum, lb+6);
    if ((tid&7)==0){
      __builtin_amdgcn_s_setprio(1);
      int jj = tid>>3;
      float cc = sigf(g_f)*cloc[layer][jj] + sigf(g_i)*tanhf(g_g);
      float hh = sigf(g_o)*tanhf(cc);
      cloc[layer][jj]=cc; hown[layer][jj]=hh;
      ast64(Hw + p*64 + jj, pk(hh, tag));
      __builtin_amdgcn_s_setprio(0);
    }
  };

  // LSTM with register-resident weights (stage B) — no L2 weight traffic.
  auto lstm_reg = [&](int layer, ull* Hw, unsigned tag){
    const float* xs = xb + half*256;
    float a = 0.f;
    #pragma unroll
    for (int it8=0; it8<32; it8++){
      uint4 w = w1r[it8];
      float4 x0 = *reinterpret_cast<const float4*>(xs + it8*8);
      float4 x1 = *reinterpret_cast<const float4*>(xs + it8*8 + 4);
      a += x0.x*lo16(w.x)+x0.y*hi16(w.x)+x0.z*lo16(w.y)+x0.w*hi16(w.y)
         + x1.x*lo16(w.z)+x1.y*hi16(w.z)+x1.z*lo16(w.w)+x1.w*hi16(w.w);
    }
    a += __shfl_xor(a, 1);
    float gsum = a + bsl[layer][gidx];
    float g_i = __shfl(gsum, lb+0);
    float g_f = __shfl(gsum, lb+2);
    float g_g = __shfl(gsum, lb+4);
    float g_o = __shfl(gsum, lb+6);
    if ((tid&7)==0){
      __builtin_amdgcn_s_setprio(1);
      int jj = tid>>3;
      float cc = sigf(g_f)*cloc[layer][jj] + sigf(g_i)*tanhf(g_g);
      float hh = sigf(g_o)*tanhf(cc);
      cloc[layer][jj]=cc; hown[layer][jj]=hh;
      ast64(Hw + p*64 + jj, pk(hh, tag));
      __builtin_amdgcn_s_setprio(0);
    }
  };

  // fill xb for the next LSTM round: x_lo = exchanged h (poll remote, own from
  // LDS hown), x_hi = hnext (local prev-state). Also writes back harr[].
  auto fill_from = [&](const ull* Hw, unsigned tag, int layer, float* harr,
                       const float* hnext){
    __syncthreads();
    if (tid < 256){
      int sp = tid >> 6; float v;
      if (sp == p) v = hown[layer][tid & 63];
      else { const ull* w = Hw + tid; ull u = ald64(w);
             while ((unsigned)(u>>32) != tag) u = ald64(w);
             v = upk(u); }
      harr[tid] = v;
      if (hnext){ xb[tid] = v; xb[256+tid] = hnext[tid]; }
    }
    __syncthreads();
  };

  // attention: shfl-ized q-MLP, own l-quarter scores + softmax partials +
  // partial ctx -> tagged mailbox; exact assembly.
  // Folds next stage-A xb: xb = [ctx_new, h0].
  auto attn = [&](unsigned tag){
    { // xq: lane pairs, j=tid>>1, half k of 128; 16 uint4 tile loads
      const int j = tid>>1;
      float a = 0.f;
      #pragma unroll
      for (int k8=0;k8<16;k8++){
        uint4 w = ((const uint4*)qW0v)[k8*512 + tid];
        const float* hb = h2 + half*128 + k8*8;
        a += hb[0]*lo16(w.x)+hb[1]*hi16(w.x)
           + hb[2]*lo16(w.y)+hb[3]*hi16(w.y)
           + hb[4]*lo16(w.z)+hb[5]*hi16(w.z)
           + hb[6]*lo16(w.w)+hb[7]*hi16(w.w);
      }
      a += __shfl_xor(a, 1);
      if (half==0) xq[j] = eluf(a + b2f(qb0c[j]));
    }
    __syncthreads();
    { // qv: 8 lanes per qc (8 k-strips of 32); 4 uint4 tile loads + shfl tree
      const int qc = tid>>3, s8 = tid&7;
      float a = 0.f;
      #pragma unroll
      for (int g=0;g<4;g++){
        uint4 w = ((const uint4*)qW1v)[g*512 + tid];
        const float* xs8 = xq + s8*32 + g*8;
        a += xs8[0]*lo16(w.x)+xs8[1]*hi16(w.x)
           + xs8[2]*lo16(w.y)+xs8[3]*hi16(w.y)
           + xs8[4]*lo16(w.z)+xs8[5]*hi16(w.z)
           + xs8[6]*lo16(w.w)+xs8[7]*hi16(w.w);
      }
      a += __shfl_xor(a, 1);
      a += __shfl_xor(a, 2);
      a += __shfl_xor(a, 4);
      if (s8==0) qv[qc] = a + b2f(qb1c[qc]);
    }
    __syncthreads();
    { // scores own l-quarter: l-pairs x 4 q-chunks of 16
      const int lp = tid & 127, qh = tid >> 7;
      float a0=0.f,a1=0.f;
      const unsigned short* kp = keyT + (size_t)n*65536 + (size_t)qh*16*1024 + p*256 + 2*lp;
      #pragma unroll 8
      for (int q=0;q<16;q++){
        ushort2 w = *reinterpret_cast<const ushort2*>(kp + (size_t)q*1024);
        float qq = qv[qh*16+q];
        a0 += qq*b2f(w.x); a1 += qq*b2f(w.y);
      }
      sacc[qh*256+2*lp]=a0; sacc[qh*256+2*lp+1]=a1;
    }
    __syncthreads();
    // wave-shuffle softmax partials
    float pmax, psum;
    {
      float s = -1e30f;
      if (tid < 256){
        s = sacc[tid]+sacc[256+tid]+sacc[512+tid]+sacc[768+tid];
        if (p*256+tid >= slen) s = -1e30f;
      }
      float m = s;
      #pragma unroll
      for (int off=32; off; off>>=1) m = fmaxf(m, __shfl_xor(m, off));
      if ((tid&63)==0) red[tid>>6] = m;
      __syncthreads();
      pmax = fmaxf(fmaxf(red[0],red[1]),fmaxf(red[2],red[3]));
      float e = 0.f;
      if (tid < 256){
        e = (p*256+tid < slen) ? __expf(s - pmax) : 0.f;
        earr[tid] = e;
      }
      float ss = e;
      #pragma unroll
      for (int off=32; off; off>>=1) ss += __shfl_xor(ss, off);
      if ((tid&63)==0) red[8+(tid>>6)] = ss;
      __syncthreads();
      psum = red[8]+red[9]+red[10]+red[11];
    }
    { // partial ctx from LDS value: h-pairs x 4 l-chunks of 64
      const int hp = tid & 127, lq = tid >> 7;
      float a0=0.f,a1=0.f;
      const unsigned short* vp = vlds + (size_t)(lq*64)*256 + 2*hp;
      #pragma unroll 8
      for (int l=0;l<64;l++){
        ushort2 w = *reinterpret_cast<const ushort2*>(vp + (size_t)l*256);
        float e = earr[lq*64+l];
        a0 += e*b2f(w.x); a1 += e*b2f(w.y);
      }
      sacc[lq*256+2*hp]=a0; sacc[lq*256+2*hp+1]=a1;
    }
    __syncthreads();
    if (tid < 256){
      float v = sacc[tid]+sacc[256+tid]+sacc[512+tid]+sacc[768+tid];
      pcl[tid] = v;
      ast64(PCw + p*256 + tid, pk(v, tag));
    }
    if (tid == 0){ ast64(STw + p*2, pk(pmax, tag)); ast64(STw + p*2 + 1, pk(psum, tag)); }
    // stats gather (all 4 parts): own from registers, remote by poll
    if (tid < 8){
      int q = tid >> 1, ix = tid & 1; float v;
      if (q == p) v = ix ? psum : pmax;
      else { const ull* w = STw + q*2 + ix; ull u = ald64(w);
             while ((unsigned)(u>>32) != tag) u = ald64(w);
             v = upk(u); }
      statl[tid] = v;
    }
    __syncthreads();
    if (tid == 0){
      float m0=statl[0], s0=statl[1], m1=statl[2], s1=statl[3];
      float m2=statl[4], s2=statl[5], m3=statl[6], s3=statl[7];
      float M = fmaxf(fmaxf(m0,m1),fmaxf(m2,m3));
      float w0=__expf(m0-M), w1=__expf(m1-M), w2=__expf(m2-M), w3=__expf(m3-M);
      float inv = 1.f/(s0*w0+s1*w1+s2*w2+s3*w3);
      wf[0]=w0*inv; wf[1]=w1*inv; wf[2]=w2*inv; wf[3]=w3*inv;
    }
    __syncthreads();
    if (tid < 256){
      // parallel remote polls: issue all 3 loads before checking any tag
      const int q0=(p+1)&3, q1=(p+2)&3, q2=(p+3)&3;
      const ull* w0 = PCw + q0*256 + tid;
      const ull* w1 = PCw + q1*256 + tid;
      const ull* w2 = PCw + q2*256 + tid;
      ull u0=ald64(w0), u1=ald64(w1), u2=ald64(w2);
      while ((unsigned)(u0>>32) != tag) u0 = ald64(w0);
      while ((unsigned)(u1>>32) != tag) u1 = ald64(w1);
      while ((unsigned)(u2>>32) != tag) u2 = ald64(w2);
      float acc = pcl[tid]*wf[p] + upk(u0)*wf[q0] + upk(u1)*wf[q1] + upk(u2)*wf[q2];
      ctx[tid] = acc;
      xb[tid] = acc;             // stage-A x-half
      xb[256+tid] = h0[tid];     // stage-A h-half
    }
    __syncthreads();
  };

  attn(1);   // initial prev_ctx from inith[2] (h2 local)

  for (int t=0;t<256;t++){
    const unsigned tb = 4*(unsigned)t;
    const int lab = i64 ? labels[2*(t*64+n)] : labels[t*64+n];
    const float* ger = gep + ((size_t)p*34+lab)*256;
    // stage A: xb = {ctx, h0_prev} (folded by attn)
    lstm_stream(Wl0, 0, ger, H0w, tb+2);
    // stage B: xb = {h0_new, h1_prev}; h0[] written back
    fill_from(H0w, tb+2, 0, h0, h1);
    lstm_reg(1, H1w, tb+3);
    // stage C: xb = {h1_new, h2_prev}; h1[] written back
    fill_from(H1w, tb+3, 1, h1, h2);
    lstm_stream(Wl2, 2, nullptr, H2w, tb+4);
    // h2 full for attn/out-proj
    fill_from(H2w, tb+4, 2, h2, nullptr);
    // stage D: attention (folds xb = {ctx_new, h0} for next stage A)
    attn(tb+5);
    // out projection: rows r = 4*ri + p (+ rows 32,33 on parts 0,1)
    {
      const int ri = tid >> 6, kk = tid & 63;
      const int r = 4*ri + p;
      float acc = 0.f;
      const unsigned short* wr = outWc + (size_t)r*512 + kk;
      #pragma unroll
      for (int s=0;s<4;s++) acc += ctx[s*64+kk]*b2f(wr[s*64]);
      #pragma unroll
      for (int s=0;s<4;s++) acc += h2[s*64+kk]*b2f(wr[256+s*64]);
      #pragma unroll
      for (int off=32; off>0; off>>=1) acc += __shfl_down(acc, off);
      if (kk==0){
        float v = acc + b2f(outbc[r]);
        size_t oi = ((size_t)(t*64+n))*34 + r;
        if (f32o) ((float*)out)[oi]=v; else ((unsigned short*)out)[oi]=f2b(v);
      }
      if (p < 2 && tid < 64){
        const int r2 = 32+p;
        float a2=0.f;
        const unsigned short* wr2 = outWc + (size_t)r2*512 + tid;
        #pragma unroll
        for (int s=0;s<4;s++) a2 += ctx[s*64+tid]*b2f(wr2[s*64]);
        #pragma unroll
        for (int s=0;s<4;s++) a2 += h2[s*64+tid]*b2f(wr2[256+s*64]);
        #pragma unroll
        for (int off=32; off>0; off>>=1) a2 += __shfl_down(a2, off);
        if (tid==0){
          float v = a2 + b2f(outbc[r2]);
          size_t oi = ((size_t)(t*64+n))*34 + r2;
          if (f32o) ((float*)out)[oi]=v; else ((unsigned short*)out)[oi]=f2b(v);
        }
      }
    }
  }
}

extern "C" void kernel_launch(void* const* d_in, const int* in_sizes, int n_in,
                              void* d_out, int out_size, void* d_ws, size_t ws_size,
                              hipStream_t stream) {
  const void* seqs  = d_in[0];
  const int* seq_lens = (const int*)d_in[1];
  const int* labels   = (const int*)d_in[2];
  const void* emb   = d_in[3];
  const void* inith = d_in[4];
  const void* initc = d_in[5];
  const void* Wih0 = d_in[6];  const void* Whh0 = d_in[7];
  const void* bih0 = d_in[8];  const void* bhh0 = d_in[9];
  const void* Wih1 = d_in[10]; const void* Whh1 = d_in[11];
  const void* bih1 = d_in[12]; const void* bhh1 = d_in[13];
  const void* Wih2 = d_in[14]; const void* Whh2 = d_in[15];
  const void* bih2 = d_in[16]; const void* bhh2 = d_in[17];
  const void* qW0 = d_in[18];  const void* qb0 = d_in[19];
  const void* qW1 = d_in[20];  const void* qb1 = d_in[21];
  const void* kW0 = d_in[22];  const void* kb0 = d_in[23];
  const void* kW1 = d_in[24];  const void* kb1 = d_in[25];
  const void* vW0 = d_in[26];  const void* vb0 = d_in[27];
  const void* vW1 = d_in[28];  const void* vb1 = d_in[29];
  const void* outW = d_in[30]; const void* outb = d_in[31];

  char* ws = (char*)d_ws;
  unsigned short* keyT  = (unsigned short*)(ws);             //  8,388,608 B  [64][64][1024]
  unsigned short* value = (unsigned short*)(ws + 8388608);   // 33,554,432 B  [64][1024][256]
  unsigned short* Wl0   = (unsigned short*)(ws + 41943040);  //  1,048,576 B  [4][32][512][8]
  unsigned short* Wl1   = (unsigned short*)(ws + 42991616);
  unsigned short* Wl2   = (unsigned short*)(ws + 44040192);
  unsigned short* kW0T  = (unsigned short*)(ws + 45088768);  //    524,288 B (prep-only)
  unsigned short* kW1T  = (unsigned short*)(ws + 45613056);  //     65,536 B (prep-only)
  unsigned short* vW0T  = (unsigned short*)(ws + 45678592);  //    262,144 B (prep-only)
  unsigned short* vW1T  = (unsigned short*)(ws + 45940736);  //    131,072 B (prep-only)
  unsigned short* qW0v  = (unsigned short*)(ws + 46071808);  //    131,072 B
  unsigned short* qW1v  = (unsigned short*)(ws + 46202880);  //     32,768 B
  float*          bsum  = (float*)(ws + 46235648);           //     12,288 B  [3][4][256]
  float*          gep   = (float*)(ws + 46247936);           //    139,264 B  [4][34][256]
  unsigned short* outWc = (unsigned short*)(ws + 46387200);  //     34,816 B
  unsigned short* inithc= (unsigned short*)(ws + 46422016);  //      1,536 B
  unsigned short* initcc= (unsigned short*)(ws + 46423552);  //      1,536 B
  unsigned short* qb0c  = (unsigned short*)(ws + 46425088);  //        512 B
  unsigned short* qb1c  = (unsigned short*)(ws + 46425600);  //        128 B
  unsigned short* outbc = (unsigned short*)(ws + 46425728);  //        128 B
  int*            dflags= (int*)(ws + 46425856);             //         16 B
  // tagged mailbox overlaps kW0T..vW1T (all consumed before speller starts):
  ull* hbw = (ull*)(ws + 45088768);                          //    921,600 B  [64][1800] ull

  sniff<<<dim3(1), dim3(64), 0, stream>>>(seqs, seq_lens, dflags);
  prep_transpose<<<dim3(8472), dim3(256), 0, stream>>>(
      Wih0,Whh0,Wih1,Whh1,Wih2,Whh2, kW0,kW1,vW0,vW1,qW0,qW1,
      bih0,bhh0,bih1,bhh1,bih2,bhh2,
      outW,inith,initc,qb0,qb1,outb, dflags,
      Wl0,Wl1,Wl2,kW0T,kW1T,vW0T,vW1T,qW0v,qW1v,bsum,
      outWc,inithc,initcc,qb0c,qb1c,outbc);
  prep_ge<<<dim3(34), dim3(256), 0, stream>>>(emb, Wih0, dflags, gep);
  key_mlp<<<dim3(4096), dim3(256), 0, stream>>>(seqs, kW0T, kb0, kW1T, kb1, dflags, keyT);
  value_mlp<<<dim3(4096), dim3(256), 0, stream>>>(seqs, vW0T, vb0, vW1T, vb1, dflags, value);
  zero_hbuf<<<dim3(450), dim3(256), 0, stream>>>(hbw);
  hipFuncSetAttribute((const void*)speller, hipFuncAttributeMaxDynamicSharedMemorySize, 131072);
  speller<<<dim3(256), dim3(512), 131072, stream>>>(
      keyT, value, Wl0, Wl1, Wl2, qW0v, qW1v, bsum, gep,
      inithc, initcc, qb0c, qb1c, outWc, outbc, labels, seq_lens, dflags,
      hbw, d_out);
}

// Round 6
// 20936.691 us; speedup vs baseline: 1.3432x; 1.3432x over previous
//
#include <hip/hip_runtime.h>
#include <cstddef>

#define DEV static __device__ __forceinline__
typedef unsigned long long ull;

DEV float b2f(unsigned short u){ unsigned int i=((unsigned int)u)<<16; float f; __builtin_memcpy(&f,&i,4); return f; }
DEV float lo16(unsigned int u){ unsigned int i=u<<16; float f; __builtin_memcpy(&f,&i,4); return f; }
DEV float hi16(unsigned int u){ unsigned int i=u&0xffff0000u; float f; __builtin_memcpy(&f,&i,4); return f; }
DEV unsigned short f2b(float f){ unsigned int i; __builtin_memcpy(&i,&f,4); unsigned int r=(i+0x7fffu+((i>>16)&1u))>>16; return (unsigned short)r; }
DEV float sigf(float x){ return 1.f/(1.f+__expf(-x)); }
DEV float eluf(float x){ return x>0.f ? x : (__expf(x)-1.f); }
DEV float gload(const void* p, long i, int f32){
  return f32 ? ((const float*)p)[i] : b2f(((const unsigned short*)p)[i]);
}
// tagged-word mailbox: {tag<<32 | f32 bits}, relaxed agent atomics (LLC point).
DEV ull pk(float f, unsigned tag){ unsigned b; __builtin_memcpy(&b,&f,4); return ((ull)tag<<32)|b; }
DEV float upk(ull u){ unsigned b=(unsigned)u; float f; __builtin_memcpy(&f,&b,4); return f; }
DEV void ast64(ull* p, ull v){ __hip_atomic_store(p, v, __ATOMIC_RELAXED, __HIP_MEMORY_SCOPE_AGENT); }
DEV ull ald64(const ull* p){ return __hip_atomic_load(p, __ATOMIC_RELAXED, __HIP_MEMORY_SCOPE_AGENT); }

// ---------------------------------------------------------------------------
// Sniff input dtypes. flags[0]=1 if floats are f32; flags[1]=1 if ints are i64.
// ---------------------------------------------------------------------------
__global__ __launch_bounds__(64) void sniff(const void* __restrict__ seqs,
                                            const void* __restrict__ seq_lens,
                                            int* __restrict__ flags)
{
  __shared__ int cnt;
  if (threadIdx.x==0) cnt=0;
  __syncthreads();
  const unsigned short* u = (const unsigned short*)seqs;
  int sane=0;
  for (int i=threadIdx.x;i<1024;i+=64){
    int e = (u[i]>>7)&0xFF;
    if (e>=0x70 && e<=0x8F) sane++;
  }
  atomicAdd(&cnt, sane);
  __syncthreads();
  if (threadIdx.x==0){
    flags[0] = (cnt < 820) ? 1 : 0;
    const int* s = (const int*)seq_lens;
    flags[1] = ((s[1]|s[3]|s[5]|s[7])==0) ? 1 : 0;
  }
}

// ---------------------------------------------------------------------------
// Prep: part-sliced bf16 weights (r4-proven layout).
// Wl[l][part][k][gi]: gi in [0,256): type=gi>>6, jj=gi&63,
// g = type*256 + part*64 + jj.  k<256 -> ih (ctx/h_in), k>=256 -> hh.
// qW0v: [k8][j][kk8] tiles.  qW1v: [s16][qc][kk16] tiles.
// ---------------------------------------------------------------------------
__global__ __launch_bounds__(256) void prep_transpose(
    const void* __restrict__ Wih0, const void* __restrict__ Whh0,
    const void* __restrict__ Wih1, const void* __restrict__ Whh1,
    const void* __restrict__ Wih2, const void* __restrict__ Whh2,
    const void* __restrict__ kW0,  const void* __restrict__ kW1,
    const void* __restrict__ vW0,  const void* __restrict__ vW1,
    const void* __restrict__ qW0,  const void* __restrict__ qW1,
    const void* __restrict__ bih0, const void* __restrict__ bhh0,
    const void* __restrict__ bih1, const void* __restrict__ bhh1,
    const void* __restrict__ bih2, const void* __restrict__ bhh2,
    const void* __restrict__ outW, const void* __restrict__ inith,
    const void* __restrict__ initc, const void* __restrict__ qb0,
    const void* __restrict__ qb1,  const void* __restrict__ outb,
    const int* __restrict__ flags,
    unsigned short* __restrict__ Wl0, unsigned short* __restrict__ Wl1,
    unsigned short* __restrict__ Wl2,
    unsigned short* __restrict__ kW0T, unsigned short* __restrict__ kW1T,
    unsigned short* __restrict__ vW0T, unsigned short* __restrict__ vW1T,
    unsigned short* __restrict__ qW0v, unsigned short* __restrict__ qW1v,
    float* __restrict__ bsum,
    unsigned short* __restrict__ outWc, unsigned short* __restrict__ inithc,
    unsigned short* __restrict__ initcc, unsigned short* __restrict__ qb0c,
    unsigned short* __restrict__ qb1c,  unsigned short* __restrict__ outbc)
{
  const int f32 = flags[0];
  int idx = blockIdx.x*256 + threadIdx.x;
  if (idx < 524288){ int r=idx&131071, k=r>>8, gi=r&255;
    int g = ((gi>>6)<<8) + ((idx>>17)<<6) + (gi&63);
    Wl0[idx] = f2b((k<256)? gload(Wih0,(long)g*512+k,f32) : gload(Whh0,(long)g*256+(k-256),f32)); return; }
  idx -= 524288;
  if (idx < 524288){ int r=idx&131071, k=r>>8, gi=r&255;
    int g = ((gi>>6)<<8) + ((idx>>17)<<6) + (gi&63);
    Wl1[idx] = f2b((k<256)? gload(Wih1,(long)g*256+k,f32) : gload(Whh1,(long)g*256+(k-256),f32)); return; }
  idx -= 524288;
  if (idx < 524288){ int r=idx&131071, k=r>>8, gi=r&255;
    int g = ((gi>>6)<<8) + ((idx>>17)<<6) + (gi&63);
    Wl2[idx] = f2b((k<256)? gload(Wih2,(long)g*256+k,f32) : gload(Whh2,(long)g*256+(k-256),f32)); return; }
  idx -= 524288;
  if (idx < 262144){ int k=idx>>9, j=idx&511; kW0T[idx]=f2b(gload(kW0,(long)j*512+k,f32)); return; }
  idx -= 262144;
  if (idx < 32768){ int k=idx>>6, j=idx&63; kW1T[idx]=f2b(gload(kW1,(long)j*512+k,f32)); return; }
  idx -= 32768;
  if (idx < 131072){ int k=idx>>8, j=idx&255; vW0T[idx]=f2b(gload(vW0,(long)j*512+k,f32)); return; }
  idx -= 131072;
  if (idx < 65536){ int k=idx>>8, j=idx&255; vW1T[idx]=f2b(gload(vW1,(long)j*256+k,f32)); return; }
  idx -= 65536;
  if (idx < 65536){ // qW0v[(k8*256 + j)*8 + kk] = qW0[j][k8*8+kk]
    int k8=idx>>11, j=(idx>>3)&255, kk=idx&7; int k=k8*8+kk;
    qW0v[idx]=f2b(gload(qW0,(long)j*256+k,f32)); return; }
  idx -= 65536;
  if (idx < 16384){ // qW1v[(s*64 + qc)*16 + kk] = qW1[qc][s*16+kk]
    int s=idx>>10, qc=(idx>>4)&63, kk=idx&15; int k=s*16+kk;
    qW1v[idx]=f2b(gload(qW1,(long)qc*256+k,f32)); return; }
  idx -= 16384;
  if (idx < 3072){ int l=idx>>10, r=idx&1023, pp=r>>8, gi=r&255;
    int g = ((gi>>6)<<8) + (pp<<6) + (gi&63);
    const void* bi = (l==0)?bih0:((l==1)?bih1:bih2);
    const void* bh = (l==0)?bhh0:((l==1)?bhh1:bhh2);
    bsum[idx] = gload(bi,g,f32)+gload(bh,g,f32); return; }
  idx -= 3072;
  if (idx < 17408){ outWc[idx]=f2b(gload(outW,idx,f32)); return; }
  idx -= 17408;
  if (idx < 768){ inithc[idx]=f2b(gload(inith,idx,f32)); return; }
  idx -= 768;
  if (idx < 768){ initcc[idx]=f2b(gload(initc,idx,f32)); return; }
  idx -= 768;
  if (idx < 256){ qb0c[idx]=f2b(gload(qb0,idx,f32)); return; }
  idx -= 256;
  if (idx < 64){ qb1c[idx]=f2b(gload(qb1,idx,f32)); return; }
  idx -= 64;
  if (idx < 34){ outbc[idx]=f2b(gload(outb,idx,f32)); return; }
}

// gep[part][v][gi] = sum_k emb[v][k] * Wih0[g(part,gi)][256+k]
__global__ __launch_bounds__(256) void prep_ge(
    const void* __restrict__ emb,
    const void* __restrict__ Wih0,
    const int* __restrict__ flags,
    float* __restrict__ gep)
{
  __shared__ float ev[256];
  const int f32 = flags[0];
  const int v = blockIdx.x, tid = threadIdx.x;
  ev[tid] = gload(emb,(long)v*256+tid,f32);
  __syncthreads();
  #pragma unroll
  for (int j=0;j<4;j++){
    const int g = tid*4+j;
    float a = 0.f;
    #pragma unroll 4
    for (int k=0;k<256;k++) a += ev[k]*gload(Wih0,(long)g*512+256+k,f32);
    int pp = (g>>6)&3, gi = ((g>>8)<<6)|(g&63);
    gep[((size_t)pp*34+v)*256+gi] = a;
  }
}

// ---------------------------------------------------------------------------
// key MLP: keyT[n][q][l]  (unchanged)
// ---------------------------------------------------------------------------
__global__ __launch_bounds__(256) void key_mlp(
    const void* __restrict__ seqs,
    const unsigned short* __restrict__ kW0T, const void* __restrict__ kb0,
    const unsigned short* __restrict__ kW1T, const void* __restrict__ kb1,
    const int* __restrict__ flags,
    unsigned short* __restrict__ keyT)
{
  __shared__ float Xt[16*512];
  __shared__ unsigned short Hd[16*512];
  const int f32 = flags[0];
  const int tid = threadIdx.x;
  const int R0 = blockIdx.x*16;
  for (int i=tid;i<8192;i+=256) Xt[i] = gload(seqs,(long)R0*512+i,f32);
  __syncthreads();
  {
    const int j0 = 2*tid;
    float acc0[16], acc1[16];
    #pragma unroll
    for (int r=0;r<16;r++){ acc0[r]=0.f; acc1[r]=0.f; }
    for (int k=0;k<512;k++){
      ushort2 w = *reinterpret_cast<const ushort2*>(kW0T + (size_t)k*512 + j0);
      float w0=b2f(w.x), w1=b2f(w.y);
      #pragma unroll
      for (int r=0;r<16;r++){ float x = Xt[r*512+k]; acc0[r]+=x*w0; acc1[r]+=x*w1; }
    }
    float b0v=gload(kb0,j0,f32), b1v=gload(kb0,j0+1,f32);
    #pragma unroll
    for (int r=0;r<16;r++){
      Hd[r*512+j0]   = f2b(eluf(acc0[r]+b0v));
      Hd[r*512+j0+1] = f2b(eluf(acc1[r]+b1v));
    }
  }
  __syncthreads();
  {
    const int j = tid & 63;
    const int rbase = tid >> 6;
    float acc[4] = {0.f,0.f,0.f,0.f};
    for (int k=0;k<512;k++){
      float w = b2f(kW1T[(size_t)k*64 + j]);
      #pragma unroll
      for (int m=0;m<4;m++) acc[m] += b2f(Hd[(rbase+4*m)*512 + k]) * w;
    }
    float bv = gload(kb1,j,f32);
    #pragma unroll
    for (int m=0;m<4;m++){
      int R = R0 + rbase + 4*m;
      int l = R >> 6, n = R & 63;
      keyT[((size_t)(n*64 + j))*1024 + l] = f2b(acc[m]+bv);
    }
  }
}

// ---------------------------------------------------------------------------
// value MLP: value[n][l][h]  (unchanged)
// ---------------------------------------------------------------------------
__global__ __launch_bounds__(256) void value_mlp(
    const void* __restrict__ seqs,
    const unsigned short* __restrict__ vW0T, const void* __restrict__ vb0,
    const unsigned short* __restrict__ vW1T, const void* __restrict__ vb1,
    const int* __restrict__ flags,
    unsigned short* __restrict__ value)
{
  __shared__ float Xt[16*512];
  __shared__ float Hd[16*256];
  const int f32 = flags[0];
  const int tid = threadIdx.x;
  const int R0 = blockIdx.x*16;
  for (int i=tid;i<8192;i+=256) Xt[i] = gload(seqs,(long)R0*512+i,f32);
  __syncthreads();
  {
    const int j0 = 2*(tid & 127);
    const int rh = tid >> 7;
    float acc0[8], acc1[8];
    #pragma unroll
    for (int r=0;r<8;r++){ acc0[r]=0.f; acc1[r]=0.f; }
    for (int k=0;k<512;k++){
      ushort2 w = *reinterpret_cast<const ushort2*>(vW0T + (size_t)k*256 + j0);
      float w0=b2f(w.x), w1=b2f(w.y);
      #pragma unroll
      for (int r=0;r<8;r++){ float x = Xt[(rh*8+r)*512+k]; acc0[r]+=x*w0; acc1[r]+=x*w1; }
    }
    float b0v=gload(vb0,j0,f32), b1v=gload(vb0,j0+1,f32);
    #pragma unroll
    for (int r=0;r<8;r++){
      Hd[(rh*8+r)*256+j0]   = eluf(acc0[r]+b0v);
      Hd[(rh*8+r)*256+j0+1] = eluf(acc1[r]+b1v);
    }
  }
  __syncthreads();
  {
    const int j = tid;
    float acc[16];
    #pragma unroll
    for (int r=0;r<16;r++) acc[r]=0.f;
    for (int k=0;k<256;k++){
      float w = b2f(vW1T[(size_t)k*256 + j]);
      #pragma unroll
      for (int r=0;r<16;r++) acc[r] += Hd[r*256+k]*w;
    }
    float bv = gload(vb1,j,f32);
    #pragma unroll
    for (int r=0;r<16;r++){
      int R = R0 + r; int l = R>>6, n = R&63;
      value[((size_t)n*1024 + l)*256 + j] = f2b(acc[r]+bv);
    }
  }
}

__global__ __launch_bounds__(256) void zero_hbuf(ull* __restrict__ f){
  int i = blockIdx.x*256 + threadIdx.x;
  if (i < 115200) f[i] = 0;   // tag 0 matches no round (tags start at 1)
}

// ---------------------------------------------------------------------------
// Decode: 256 blocks x 512 threads, 1 block/CU. Block bid = n*4+p so XCD
// (bid%8) hosts a single part -> per-XCD L2 footprint ~2 MB. DO NOT remap
// (r1: FETCH x7, 3x slower). DO NOT widen blocks (r3: 2x slower). DO NOT
// re-map matvec lanes to single-acc dot products (r5: 256-deep FMA chain +
// b128 2-addr LDS reads = 4x slower; keep 8 independent accumulators).
// r4 evidence: polls find tags in ~1-2 iterations -> time is the block's OWN
// phase pipeline (weight-stream drains at barriers), not exchange latency.
// r6: stage-B weights register-resident (no L2 stream, no drain); out-proj
// hoisted into stage-A's pre-barrier latency slack; label prefetch.
// Mailbox per n (ull): H0[256] H1[256] H2[256] PCTX[4][256] STAT[4][2].
// ---------------------------------------------------------------------------
__global__ __launch_bounds__(512, 1) void speller(
    const unsigned short* __restrict__ keyT,
    const unsigned short* __restrict__ value,
    const unsigned short* __restrict__ Wl0,
    const unsigned short* __restrict__ Wl1,
    const unsigned short* __restrict__ Wl2,
    const unsigned short* __restrict__ qW0v,
    const unsigned short* __restrict__ qW1v,
    const float* __restrict__ bsum_p,
    const float* __restrict__ gep,
    const unsigned short* __restrict__ inithc,
    const unsigned short* __restrict__ initcc,
    const unsigned short* __restrict__ qb0c,
    const unsigned short* __restrict__ qb1c,
    const unsigned short* __restrict__ outWc,
    const unsigned short* __restrict__ outbc,
    const int* __restrict__ labels,
    const int* __restrict__ seq_lens,
    const int* __restrict__ dflags,
    ull* __restrict__ hbw,
    void* __restrict__ out)
{
  extern __shared__ char smem_dyn[];
  unsigned short* vlds = (unsigned short*)smem_dyn;   // [256 l][256 h] quarter, 128 KB

  __shared__ float sacc[4096];
  __shared__ float inc[512];
  __shared__ float garr[256];
  __shared__ float h0[256], h1[256], h2[256], ctx[256];
  __shared__ float cloc[3][64];
  __shared__ float xq[256];
  __shared__ float qv[64];
  __shared__ float earr[256];
  __shared__ float red[16];
  __shared__ float wf[4];
  __shared__ float pcl[256];
  __shared__ float statl[8];

  const int tid = threadIdx.x;
  const int n = blockIdx.x >> 2;     // bid = n*4 + p
  const int p = blockIdx.x & 3;
  const int f32o = dflags[0];
  const int i64 = dflags[1];
  const int slen = i64 ? seq_lens[2*n] : seq_lens[n];

  ull* mb   = hbw + (size_t)n*1800;
  ull* H0w  = mb;            // [256]
  ull* H1w  = mb + 256;      // [256]
  ull* H2w  = mb + 512;      // [256]
  ull* PCw  = mb + 768;      // [4][256]
  ull* STw  = mb + 1792;     // [4][2]

  // preload value quarter into LDS (once)
  {
    const uint4* src = (const uint4*)(value + ((size_t)n*1024 + p*256)*256);
    uint4* dst = (uint4*)vlds;
    for (int i=tid;i<16384;i+=512) dst[i] = src[i];
  }
  if (tid < 256){ h0[tid]=b2f(inithc[tid]); h1[tid]=b2f(inithc[256+tid]); h2[tid]=b2f(inithc[512+tid]); }
  if (tid < 64){
    cloc[0][tid]=b2f(initcc[p*64+tid]);
    cloc[1][tid]=b2f(initcc[256+p*64+tid]);
    cloc[2][tid]=b2f(initcc[512+p*64+tid]);
  }
  // stage-B weights register-resident: 32 uint4/thread (128 VGPR), the r4
  // lane map (go8=tid&31 -> 8 gates, ks=tid>>5 -> 32-k strip). Loaded once,
  // reused 256 steps; removes one 256KB L2 stream + barrier drain per step.
  const int go8 = tid & 31, ks = tid >> 5;
  uint4 w1r[32];
  {
    const unsigned short* wp1 = Wl1 + (size_t)p*131072 + (size_t)ks*32*256 + go8*8;
    #pragma unroll
    for (int k=0;k<32;k++) w1r[k] = *reinterpret_cast<const uint4*>(wp1 + (size_t)k*256);
  }
  __syncthreads();

  // out projection (rows r = 4*ri + p, + rows 32,33 on parts 0,1). Reads only
  // ctx/h2 (stable between attn and the next stage-C) -> runs inside stage-A's
  // pre-barrier slot, overlapped with the stage-A weight-load latency.
  auto outproj = [&](int t){
    const int ri = tid >> 6, kk = tid & 63;
    const int r = 4*ri + p;
    float acc = 0.f;
    const unsigned short* wr = outWc + (size_t)r*512 + kk;
    #pragma unroll
    for (int s=0;s<4;s++) acc += ctx[s*64+kk]*b2f(wr[s*64]);
    #pragma unroll
    for (int s=0;s<4;s++) acc += h2[s*64+kk]*b2f(wr[256+s*64]);
    #pragma unroll
    for (int off=32; off>0; off>>=1) acc += __shfl_down(acc, off);
    if (kk==0){
      float v = acc + b2f(outbc[r]);
      size_t oi = ((size_t)(t*64+n))*34 + r;
      if (f32o) ((float*)out)[oi]=v; else ((unsigned short*)out)[oi]=f2b(v);
    }
    if (p < 2 && tid < 64){
      const int r2 = 32+p;
      float a2=0.f;
      const unsigned short* wr2 = outWc + (size_t)r2*512 + tid;
      #pragma unroll
      for (int s=0;s<4;s++) a2 += ctx[s*64+tid]*b2f(wr2[s*64]);
      #pragma unroll
      for (int s=0;s<4;s++) a2 += h2[s*64+tid]*b2f(wr2[256+s*64]);
      #pragma unroll
      for (int off=32; off>0; off>>=1) a2 += __shfl_down(a2, off);
      if (tid==0){
        float v = a2 + b2f(outbc[r2]);
        size_t oi = ((size_t)(t*64+n))*34 + r2;
        if (f32o) ((float*)out)[oi]=v; else ((unsigned short*)out)[oi]=f2b(v);
      }
    }
  };

  // Stage-A LSTM: x from inc[512] (LDS, built by attn fold). Own h slice ->
  // mailbox only. tprev>=0: previous step's out-proj runs in the pre-barrier
  // slot (overlaps this stage's weight-load latency).
  auto lstm_lds = [&](const unsigned short* W, const float* bs, const float* ger,
                      int layer, ull* Hw, unsigned tag, int tprev){
    const unsigned short* wp = W + (size_t)p*131072 + (size_t)ks*32*256 + go8*8;
    const float* xin = inc + ks*32;
    float a0=0.f,a1=0.f,a2=0.f,a3=0.f,a4=0.f,a5=0.f,a6=0.f,a7=0.f;
    #pragma unroll 16
    for (int k=0;k<32;k++){
      float x = xin[k];
      uint4 w = *reinterpret_cast<const uint4*>(wp + (size_t)k*256);
      a0 += x*lo16(w.x); a1 += x*hi16(w.x);
      a2 += x*lo16(w.y); a3 += x*hi16(w.y);
      a4 += x*lo16(w.z); a5 += x*hi16(w.z);
      a6 += x*lo16(w.w); a7 += x*hi16(w.w);
    }
    float* sb = sacc + ks*256 + go8*8;
    sb[0]=a0; sb[1]=a1; sb[2]=a2; sb[3]=a3; sb[4]=a4; sb[5]=a5; sb[6]=a6; sb[7]=a7;
    if (tprev >= 0) outproj(tprev);
    __syncthreads();
    if (tid < 256){
      float s = bs[tid] + (ger ? ger[tid] : 0.f);
      #pragma unroll
      for (int u=0;u<16;u++) s += sacc[u*256+tid];
      garr[tid] = s;
    }
    __syncthreads();
    if (tid < 64){
      __builtin_amdgcn_s_setprio(1);
      float gi=garr[tid], gf=garr[64+tid], gg=garr[128+tid], go=garr[192+tid];
      float cc = sigf(gf)*cloc[layer][tid] + sigf(gi)*tanhf(gg);
      float hh = sigf(go)*tanhf(cc);
      cloc[layer][tid]=cc;
      ast64(Hw + p*64 + tid, pk(hh, tag));
      __builtin_amdgcn_s_setprio(0);
    }
    // no trailing barrier; next phase's sacc writes are safe (reduce done)
  };

  // Fused-poll LSTM, streamed weights (stage C): x-half (waves 0-3) polled
  // per-lane from mailbox Xw and distributed via __shfl; h-half (waves 4-7)
  // from LDS hprev, starts immediately. Polled x written back to xdst[].
  auto lstm_poll = [&](const unsigned short* W, const float* bs,
                       const ull* Xw, unsigned xtag, const float* hprev,
                       float* xdst, int layer, ull* Hw, unsigned tag){
    const int lane = tid & 63, wv = tid >> 6;
    float xv;
    if (wv < 4){
      const ull* wd = Xw + tid;
      ull u = ald64(wd);
      while ((unsigned)(u>>32) != xtag) u = ald64(wd);
      xv = upk(u);
    } else {
      xv = hprev[tid - 256];
    }
    const unsigned short* wp = W + (size_t)p*131072 + (size_t)ks*32*256 + go8*8;
    float a0=0.f,a1=0.f,a2=0.f,a3=0.f,a4=0.f,a5=0.f,a6=0.f,a7=0.f;
    #pragma unroll 16
    for (int k=0;k<32;k++){
      float x = __shfl(xv, (lane & 32) | k);
      uint4 w = *reinterpret_cast<const uint4*>(wp + (size_t)k*256);
      a0 += x*lo16(w.x); a1 += x*hi16(w.x);
      a2 += x*lo16(w.y); a3 += x*hi16(w.y);
      a4 += x*lo16(w.z); a5 += x*hi16(w.z);
      a6 += x*lo16(w.w); a7 += x*hi16(w.w);
    }
    float* sb = sacc + ks*256 + go8*8;
    sb[0]=a0; sb[1]=a1; sb[2]=a2; sb[3]=a3; sb[4]=a4; sb[5]=a5; sb[6]=a6; sb[7]=a7;
    if (wv < 4) xdst[tid] = xv;     // h-full writeback (gather eliminated)
    __syncthreads();
    if (tid < 256){
      float s = bs[tid];
      #pragma unroll
      for (int u=0;u<16;u++) s += sacc[u*256+tid];
      garr[tid] = s;
    }
    __syncthreads();
    if (tid < 64){
      __builtin_amdgcn_s_setprio(1);
      float gi=garr[tid], gf=garr[64+tid], gg=garr[128+tid], go=garr[192+tid];
      float cc = sigf(gf)*cloc[layer][tid] + sigf(gi)*tanhf(gg);
      float hh = sigf(go)*tanhf(cc);
      cloc[layer][tid]=cc;
      ast64(Hw + p*64 + tid, pk(hh, tag));
      __builtin_amdgcn_s_setprio(0);
    }
  };

  // Fused-poll LSTM, register weights (stage B): same as lstm_poll but the
  // matvec reads w1r (no global loads at all). Full unroll keeps w1r indices
  // compile-time constant (rule: runtime-indexed reg arrays go to scratch).
  auto lstm_poll_reg = [&](const float* bs,
                           const ull* Xw, unsigned xtag, const float* hprev,
                           float* xdst, int layer, ull* Hw, unsigned tag){
    const int lane = tid & 63, wv = tid >> 6;
    float xv;
    if (wv < 4){
      const ull* wd = Xw + tid;
      ull u = ald64(wd);
      while ((unsigned)(u>>32) != xtag) u = ald64(wd);
      xv = upk(u);
    } else {
      xv = hprev[tid - 256];
    }
    float a0=0.f,a1=0.f,a2=0.f,a3=0.f,a4=0.f,a5=0.f,a6=0.f,a7=0.f;
    #pragma unroll
    for (int k=0;k<32;k++){
      float x = __shfl(xv, (lane & 32) | k);
      uint4 w = w1r[k];
      a0 += x*lo16(w.x); a1 += x*hi16(w.x);
      a2 += x*lo16(w.y); a3 += x*hi16(w.y);
      a4 += x*lo16(w.z); a5 += x*hi16(w.z);
      a6 += x*lo16(w.w); a7 += x*hi16(w.w);
    }
    float* sb = sacc + ks*256 + go8*8;
    sb[0]=a0; sb[1]=a1; sb[2]=a2; sb[3]=a3; sb[4]=a4; sb[5]=a5; sb[6]=a6; sb[7]=a7;
    if (wv < 4) xdst[tid] = xv;
    __syncthreads();
    if (tid < 256){
      float s = bs[tid];
      #pragma unroll
      for (int u=0;u<16;u++) s += sacc[u*256+tid];
      garr[tid] = s;
    }
    __syncthreads();
    if (tid < 64){
      __builtin_amdgcn_s_setprio(1);
      float gi=garr[tid], gf=garr[64+tid], gg=garr[128+tid], go=garr[192+tid];
      float cc = sigf(gf)*cloc[layer][tid] + sigf(gi)*tanhf(gg);
      float hh = sigf(go)*tanhf(cc);
      cloc[layer][tid]=cc;
      ast64(Hw + p*64 + tid, pk(hh, tag));
      __builtin_amdgcn_s_setprio(0);
    }
  };

  // h2 gather: all 256 words polled from mailbox (own slice included).
  auto gather_h2 = [&](unsigned tag){
    if (tid < 256){
      const ull* w = H2w + tid; ull u = ald64(w);
      while ((unsigned)(u>>32) != tag) u = ald64(w);
      h2[tid] = upk(u);
    }
    __syncthreads();
  };

  // attention: replicated q-MLP from full h2 (LDS), own l-quarter scores +
  // softmax partials + partial ctx -> tagged mailbox; exact assembly.
  // Folds next stage-A inc copy: inc = [ctx_new, h0].
  auto attn = [&](unsigned tag){
    { // xq: j=tid&255, kh=tid>>8 -> 16 coalesced uint4 loads (qW0v tiles)
      const int j = tid & 255, kh = tid >> 8;
      const uint4* qp = (const uint4*)qW0v + (size_t)(kh*16)*256 + j;
      float a = 0.f;
      #pragma unroll
      for (int k8=0;k8<16;k8++){
        uint4 w = qp[(size_t)k8*256];
        const float* hb = h2 + kh*128 + k8*8;
        a += hb[0]*lo16(w.x)+hb[1]*hi16(w.x)
           + hb[2]*lo16(w.y)+hb[3]*hi16(w.y)
           + hb[4]*lo16(w.z)+hb[5]*hi16(w.z)
           + hb[6]*lo16(w.w)+hb[7]*hi16(w.w);
      }
      sacc[kh*256 + j] = a;
    }
    __syncthreads();
    if (tid < 256) xq[tid] = eluf(sacc[tid]+sacc[256+tid] + b2f(qb0c[tid]));
    __syncthreads();
    { // qv: qc=tid&63, s=tid>>6 (8 k-strips of 32) -> 2x2 uint4 tile loads
      const int qc = tid & 63, s = tid >> 6;
      const uint4* qp = (const uint4*)qW1v + (size_t)(2*s*64+qc)*2;
      float a = 0.f;
      #pragma unroll
      for (int half=0;half<2;half++){
        const uint4* qph = qp + (size_t)half*64*2;
        #pragma unroll
        for (int u=0;u<2;u++){
          uint4 w = qph[u];
          const float* xb = xq + s*32 + half*16 + u*8;
          a += xb[0]*lo16(w.x)+xb[1]*hi16(w.x)
             + xb[2]*lo16(w.y)+xb[3]*hi16(w.y)
             + xb[4]*lo16(w.z)+xb[5]*hi16(w.z)
             + xb[6]*lo16(w.w)+xb[7]*hi16(w.w);
        }
      }
      sacc[s*64+qc] = a;
    }
    __syncthreads();
    if (tid < 64){
      float s=0.f;
      #pragma unroll
      for (int u=0;u<8;u++) s += sacc[u*64+tid];
      qv[tid] = s + b2f(qb1c[tid]);
    }
    __syncthreads();
    { // scores own l-quarter: l-pairs x 4 q-chunks of 16
      const int lp = tid & 127, qh = tid >> 7;
      float a0=0.f,a1=0.f;
      const unsigned short* kp = keyT + (size_t)n*65536 + (size_t)qh*16*1024 + p*256 + 2*lp;
      #pragma unroll 8
      for (int q=0;q<16;q++){
        ushort2 w = *reinterpret_cast<const ushort2*>(kp + (size_t)q*1024);
        float qq = qv[qh*16+q];
        a0 += qq*b2f(w.x); a1 += qq*b2f(w.y);
      }
      sacc[qh*256+2*lp]=a0; sacc[qh*256+2*lp+1]=a1;
    }
    __syncthreads();
    // wave-shuffle softmax partials
    float pmax, psum;
    {
      float s = -1e30f;
      if (tid < 256){
        s = sacc[tid]+sacc[256+tid]+sacc[512+tid]+sacc[768+tid];
        if (p*256+tid >= slen) s = -1e30f;
      }
      float m = s;
      #pragma unroll
      for (int off=32; off; off>>=1) m = fmaxf(m, __shfl_xor(m, off));
      if ((tid&63)==0) red[tid>>6] = m;
      __syncthreads();
      pmax = fmaxf(fmaxf(red[0],red[1]),fmaxf(red[2],red[3]));
      float e = 0.f;
      if (tid < 256){
        e = (p*256+tid < slen) ? __expf(s - pmax) : 0.f;
        earr[tid] = e;
      }
      float ss = e;
      #pragma unroll
      for (int off=32; off; off>>=1) ss += __shfl_xor(ss, off);
      if ((tid&63)==0) red[8+(tid>>6)] = ss;
      __syncthreads();
      psum = red[8]+red[9]+red[10]+red[11];
    }
    { // partial ctx from LDS value: h-pairs x 4 l-chunks of 64
      const int hp = tid & 127, lq = tid >> 7;
      float a0=0.f,a1=0.f;
      const unsigned short* vp = vlds + (size_t)(lq*64)*256 + 2*hp;
      #pragma unroll 8
      for (int l=0;l<64;l++){
        ushort2 w = *reinterpret_cast<const ushort2*>(vp + (size_t)l*256);
        float e = earr[lq*64+l];
        a0 += e*b2f(w.x); a1 += e*b2f(w.y);
      }
      sacc[lq*256+2*hp]=a0; sacc[lq*256+2*hp+1]=a1;
    }
    __syncthreads();
    if (tid < 256){
      float v = sacc[tid]+sacc[256+tid]+sacc[512+tid]+sacc[768+tid];
      pcl[tid] = v;
      ast64(PCw + p*256 + tid, pk(v, tag));
    }
    if (tid == 0){ ast64(STw + p*2, pk(pmax, tag)); ast64(STw + p*2 + 1, pk(psum, tag)); }
    // stats gather (all 4 parts): own from registers, remote by poll
    if (tid < 8){
      int q = tid >> 1, ix = tid & 1; float v;
      if (q == p) v = ix ? psum : pmax;
      else { const ull* w = STw + q*2 + ix; ull u = ald64(w);
             while ((unsigned)(u>>32) != tag) u = ald64(w);
             v = upk(u); }
      statl[tid] = v;
    }
    __syncthreads();
    if (tid == 0){
      float m0=statl[0], s0=statl[1], m1=statl[2], s1=statl[3];
      float m2=statl[4], s2=statl[5], m3=statl[6], s3=statl[7];
      float M = fmaxf(fmaxf(m0,m1),fmaxf(m2,m3));
      float w0=__expf(m0-M), w1=__expf(m1-M), w2=__expf(m2-M), w3=__expf(m3-M);
      float inv = 1.f/(s0*w0+s1*w1+s2*w2+s3*w3);
      wf[0]=w0*inv; wf[1]=w1*inv; wf[2]=w2*inv; wf[3]=w3*inv;
    }
    __syncthreads();
    if (tid < 256){
      // parallel remote polls: issue all 3 loads before checking any tag
      const int q0=(p+1)&3, q1=(p+2)&3, q2=(p+3)&3;
      const ull* w0 = PCw + q0*256 + tid;
      const ull* w1 = PCw + q1*256 + tid;
      const ull* w2 = PCw + q2*256 + tid;
      ull u0=ald64(w0), u1=ald64(w1), u2=ald64(w2);
      while ((unsigned)(u0>>32) != tag) u0 = ald64(w0);
      while ((unsigned)(u1>>32) != tag) u1 = ald64(w1);
      while ((unsigned)(u2>>32) != tag) u2 = ald64(w2);
      float acc = pcl[tid]*wf[p] + upk(u0)*wf[q0] + upk(u1)*wf[q1] + upk(u2)*wf[q2];
      ctx[tid] = acc;
      inc[tid] = acc;            // stage-A x-half
      inc[256+tid] = h0[tid];    // stage-A h-half (h0 from stage-B writeback)
    }
    __syncthreads();
  };

  attn(1);   // initial prev_ctx from inith[2] (h2 local)

  int lab = i64 ? labels[2*n] : labels[n];
  for (int t=0;t<256;t++){
    const unsigned tb = 4*(unsigned)t;
    const float* ger = gep + ((size_t)p*34+lab)*256;
    // prefetch next label (latency spans the whole step)
    int lab_next = 0;
    if (t < 255) lab_next = i64 ? labels[2*((t+1)*64+n)] : labels[(t+1)*64+n];
    // stage A: inc = {ctx, h0_prev} (folded by attn); out-proj(t-1) overlapped
    lstm_lds(Wl0, bsum_p + p*256, ger, 0, H0w, tb+2, t-1);
    // stage B: x = h0_new (fused poll), h = h1_prev; reg-resident weights
    lstm_poll_reg(bsum_p + 1024 + p*256, H0w, tb+2, h1, h0, 1, H1w, tb+3);
    // stage C: x = h1_new (fused poll), h = h2_prev; h1[] updated
    lstm_poll(Wl2, bsum_p + 2048 + p*256, H1w, tb+3, h2, h1, 2, H2w, tb+4);
    // h2 full for attn/out-proj
    gather_h2(tb+4);
    // stage D: attention (folds inc = {ctx_new, h0} for next stage A)
    attn(tb+5);
    lab = lab_next;
  }
  outproj(255);
}

extern "C" void kernel_launch(void* const* d_in, const int* in_sizes, int n_in,
                              void* d_out, int out_size, void* d_ws, size_t ws_size,
                              hipStream_t stream) {
  const void* seqs  = d_in[0];
  const int* seq_lens = (const int*)d_in[1];
  const int* labels   = (const int*)d_in[2];
  const void* emb   = d_in[3];
  const void* inith = d_in[4];
  const void* initc = d_in[5];
  const void* Wih0 = d_in[6];  const void* Whh0 = d_in[7];
  const void* bih0 = d_in[8];  const void* bhh0 = d_in[9];
  const void* Wih1 = d_in[10]; const void* Whh1 = d_in[11];
  const void* bih1 = d_in[12]; const void* bhh1 = d_in[13];
  const void* Wih2 = d_in[14]; const void* Whh2 = d_in[15];
  const void* bih2 = d_in[16]; const void* bhh2 = d_in[17];
  const void* qW0 = d_in[18];  const void* qb0 = d_in[19];
  const void* qW1 = d_in[20];  const void* qb1 = d_in[21];
  const void* kW0 = d_in[22];  const void* kb0 = d_in[23];
  const void* kW1 = d_in[24];  const void* kb1 = d_in[25];
  const void* vW0 = d_in[26];  const void* vb0 = d_in[27];
  const void* vW1 = d_in[28];  const void* vb1 = d_in[29];
  const void* outW = d_in[30]; const void* outb = d_in[31];

  char* ws = (char*)d_ws;
  unsigned short* keyT  = (unsigned short*)(ws);             //  8,388,608 B  [64][64][1024]
  unsigned short* value = (unsigned short*)(ws + 8388608);   // 33,554,432 B  [64][1024][256]
  unsigned short* Wl0   = (unsigned short*)(ws + 41943040);  //  1,048,576 B  [4][512][256]
  unsigned short* Wl1   = (unsigned short*)(ws + 42991616);
  unsigned short* Wl2   = (unsigned short*)(ws + 44040192);
  unsigned short* kW0T  = (unsigned short*)(ws + 45088768);  //    524,288 B (prep-only)
  unsigned short* kW1T  = (unsigned short*)(ws + 45613056);  //     65,536 B (prep-only)
  unsigned short* vW0T  = (unsigned short*)(ws + 45678592);  //    262,144 B (prep-only)
  unsigned short* vW1T  = (unsigned short*)(ws + 45940736);  //    131,072 B (prep-only)
  unsigned short* qW0v  = (unsigned short*)(ws + 46071808);  //    131,072 B
  unsigned short* qW1v  = (unsigned short*)(ws + 46202880);  //     32,768 B
  float*          bsum  = (float*)(ws + 46235648);           //     12,288 B  [3][4][256]
  float*          gep   = (float*)(ws + 46247936);           //    139,264 B  [4][34][256]
  unsigned short* outWc = (unsigned short*)(ws + 46387200);  //     34,816 B
  unsigned short* inithc= (unsigned short*)(ws + 46422016);  //      1,536 B
  unsigned short* initcc= (unsigned short*)(ws + 46423552);  //      1,536 B
  unsigned short* qb0c  = (unsigned short*)(ws + 46425088);  //        512 B
  unsigned short* qb1c  = (unsigned short*)(ws + 46425600);  //        128 B
  unsigned short* outbc = (unsigned short*)(ws + 46425728);  //        128 B
  int*            dflags= (int*)(ws + 46425856);             //         16 B
  // tagged mailbox overlaps kW0T..vW1T (all consumed before speller starts):
  ull* hbw = (ull*)(ws + 45088768);                          //    921,600 B  [64][1800] ull

  sniff<<<dim3(1), dim3(64), 0, stream>>>(seqs, seq_lens, dflags);
  prep_transpose<<<dim3(8472), dim3(256), 0, stream>>>(
      Wih0,Whh0,Wih1,Whh1,Wih2,Whh2, kW0,kW1,vW0,vW1,qW0,qW1,
      bih0,bhh0,bih1,bhh1,bih2,bhh2,
      outW,inith,initc,qb0,qb1,outb, dflags,
      Wl0,Wl1,Wl2,kW0T,kW1T,vW0T,vW1T,qW0v,qW1v,bsum,
      outWc,inithc,initcc,qb0c,qb1c,outbc);
  prep_ge<<<dim3(34), dim3(256), 0, stream>>>(emb, Wih0, dflags, gep);
  key_mlp<<<dim3(4096), dim3(256), 0, stream>>>(seqs, kW0T, kb0, kW1T, kb1, dflags, keyT);
  value_mlp<<<dim3(4096), dim3(256), 0, stream>>>(seqs, vW0T, vb0, vW1T, vb1, dflags, value);
  zero_hbuf<<<dim3(450), dim3(256), 0, stream>>>(hbw);
  hipFuncSetAttribute((const void*)speller, hipFuncAttributeMaxDynamicSharedMemorySize, 131072);
  speller<<<dim3(256), dim3(512), 131072, stream>>>(
      keyT, value, Wl0, Wl1, Wl2, qW0v, qW1v, bsum, gep,
      inithc, initcc, qb0c, qb1c, outWc, outbc, labels, seq_lens, dflags,
      hbw, d_out);
}

// Round 7
// 19696.774 us; speedup vs baseline: 1.4278x; 1.0630x over previous
//
#include <hip/hip_runtime.h>
#include <cstddef>

#define DEV static __device__ __forceinline__
typedef unsigned long long ull;

DEV float b2f(unsigned short u){ unsigned int i=((unsigned int)u)<<16; float f; __builtin_memcpy(&f,&i,4); return f; }
DEV float lo16(unsigned int u){ unsigned int i=u<<16; float f; __builtin_memcpy(&f,&i,4); return f; }
DEV float hi16(unsigned int u){ unsigned int i=u&0xffff0000u; float f; __builtin_memcpy(&f,&i,4); return f; }
DEV unsigned short f2b(float f){ unsigned int i; __builtin_memcpy(&i,&f,4); unsigned int r=(i+0x7fffu+((i>>16)&1u))>>16; return (unsigned short)r; }
DEV float sigf(float x){ return 1.f/(1.f+__expf(-x)); }
DEV float eluf(float x){ return x>0.f ? x : (__expf(x)-1.f); }
DEV float gload(const void* p, long i, int f32){
  return f32 ? ((const float*)p)[i] : b2f(((const unsigned short*)p)[i]);
}
// tagged-word mailbox: {tag<<32 | f32 bits}, relaxed agent atomics (LLC point).
DEV ull pk(float f, unsigned tag){ unsigned b; __builtin_memcpy(&b,&f,4); return ((ull)tag<<32)|b; }
DEV float upk(ull u){ unsigned b=(unsigned)u; float f; __builtin_memcpy(&f,&b,4); return f; }
DEV void ast64(ull* p, ull v){ __hip_atomic_store(p, v, __ATOMIC_RELAXED, __HIP_MEMORY_SCOPE_AGENT); }
DEV ull ald64(const ull* p){ return __hip_atomic_load(p, __ATOMIC_RELAXED, __HIP_MEMORY_SCOPE_AGENT); }

// ---------------------------------------------------------------------------
// Sniff input dtypes. flags[0]=1 if floats are f32; flags[1]=1 if ints are i64.
// ---------------------------------------------------------------------------
__global__ __launch_bounds__(64) void sniff(const void* __restrict__ seqs,
                                            const void* __restrict__ seq_lens,
                                            int* __restrict__ flags)
{
  __shared__ int cnt;
  if (threadIdx.x==0) cnt=0;
  __syncthreads();
  const unsigned short* u = (const unsigned short*)seqs;
  int sane=0;
  for (int i=threadIdx.x;i<1024;i+=64){
    int e = (u[i]>>7)&0xFF;
    if (e>=0x70 && e<=0x8F) sane++;
  }
  atomicAdd(&cnt, sane);
  __syncthreads();
  if (threadIdx.x==0){
    flags[0] = (cnt < 820) ? 1 : 0;
    const int* s = (const int*)seq_lens;
    flags[1] = ((s[1]|s[3]|s[5]|s[7])==0) ? 1 : 0;
  }
}

// ---------------------------------------------------------------------------
// Prep: part-sliced bf16 weights (r4-proven layout).
// Wl[l][part][k][gi]: gi in [0,256): type=gi>>6, jj=gi&63,
// g = type*256 + part*64 + jj.  k<256 -> ih (ctx/h_in), k>=256 -> hh.
// qW0v: [k8][j][kk8] tiles.  qW1v: [s16][qc][kk16] tiles.
// ---------------------------------------------------------------------------
__global__ __launch_bounds__(256) void prep_transpose(
    const void* __restrict__ Wih0, const void* __restrict__ Whh0,
    const void* __restrict__ Wih1, const void* __restrict__ Whh1,
    const void* __restrict__ Wih2, const void* __restrict__ Whh2,
    const void* __restrict__ kW0,  const void* __restrict__ kW1,
    const void* __restrict__ vW0,  const void* __restrict__ vW1,
    const void* __restrict__ qW0,  const void* __restrict__ qW1,
    const void* __restrict__ bih0, const void* __restrict__ bhh0,
    const void* __restrict__ bih1, const void* __restrict__ bhh1,
    const void* __restrict__ bih2, const void* __restrict__ bhh2,
    const void* __restrict__ outW, const void* __restrict__ inith,
    const void* __restrict__ initc, const void* __restrict__ qb0,
    const void* __restrict__ qb1,  const void* __restrict__ outb,
    const int* __restrict__ flags,
    unsigned short* __restrict__ Wl0, unsigned short* __restrict__ Wl1,
    unsigned short* __restrict__ Wl2,
    unsigned short* __restrict__ kW0T, unsigned short* __restrict__ kW1T,
    unsigned short* __restrict__ vW0T, unsigned short* __restrict__ vW1T,
    unsigned short* __restrict__ qW0v, unsigned short* __restrict__ qW1v,
    float* __restrict__ bsum,
    unsigned short* __restrict__ outWc, unsigned short* __restrict__ inithc,
    unsigned short* __restrict__ initcc, unsigned short* __restrict__ qb0c,
    unsigned short* __restrict__ qb1c,  unsigned short* __restrict__ outbc)
{
  const int f32 = flags[0];
  int idx = blockIdx.x*256 + threadIdx.x;
  if (idx < 524288){ int r=idx&131071, k=r>>8, gi=r&255;
    int g = ((gi>>6)<<8) + ((idx>>17)<<6) + (gi&63);
    Wl0[idx] = f2b((k<256)? gload(Wih0,(long)g*512+k,f32) : gload(Whh0,(long)g*256+(k-256),f32)); return; }
  idx -= 524288;
  if (idx < 524288){ int r=idx&131071, k=r>>8, gi=r&255;
    int g = ((gi>>6)<<8) + ((idx>>17)<<6) + (gi&63);
    Wl1[idx] = f2b((k<256)? gload(Wih1,(long)g*256+k,f32) : gload(Whh1,(long)g*256+(k-256),f32)); return; }
  idx -= 524288;
  if (idx < 524288){ int r=idx&131071, k=r>>8, gi=r&255;
    int g = ((gi>>6)<<8) + ((idx>>17)<<6) + (gi&63);
    Wl2[idx] = f2b((k<256)? gload(Wih2,(long)g*256+k,f32) : gload(Whh2,(long)g*256+(k-256),f32)); return; }
  idx -= 524288;
  if (idx < 262144){ int k=idx>>9, j=idx&511; kW0T[idx]=f2b(gload(kW0,(long)j*512+k,f32)); return; }
  idx -= 262144;
  if (idx < 32768){ int k=idx>>6, j=idx&63; kW1T[idx]=f2b(gload(kW1,(long)j*512+k,f32)); return; }
  idx -= 32768;
  if (idx < 131072){ int k=idx>>8, j=idx&255; vW0T[idx]=f2b(gload(vW0,(long)j*512+k,f32)); return; }
  idx -= 131072;
  if (idx < 65536){ int k=idx>>8, j=idx&255; vW1T[idx]=f2b(gload(vW1,(long)j*256+k,f32)); return; }
  idx -= 65536;
  if (idx < 65536){ // qW0v[(k8*256 + j)*8 + kk] = qW0[j][k8*8+kk]
    int k8=idx>>11, j=(idx>>3)&255, kk=idx&7; int k=k8*8+kk;
    qW0v[idx]=f2b(gload(qW0,(long)j*256+k,f32)); return; }
  idx -= 65536;
  if (idx < 16384){ // qW1v[(s*64 + qc)*16 + kk] = qW1[qc][s*16+kk]
    int s=idx>>10, qc=(idx>>4)&63, kk=idx&15; int k=s*16+kk;
    qW1v[idx]=f2b(gload(qW1,(long)qc*256+k,f32)); return; }
  idx -= 16384;
  if (idx < 3072){ int l=idx>>10, r=idx&1023, pp=r>>8, gi=r&255;
    int g = ((gi>>6)<<8) + (pp<<6) + (gi&63);
    const void* bi = (l==0)?bih0:((l==1)?bih1:bih2);
    const void* bh = (l==0)?bhh0:((l==1)?bhh1:bhh2);
    bsum[idx] = gload(bi,g,f32)+gload(bh,g,f32); return; }
  idx -= 3072;
  if (idx < 17408){ outWc[idx]=f2b(gload(outW,idx,f32)); return; }
  idx -= 17408;
  if (idx < 768){ inithc[idx]=f2b(gload(inith,idx,f32)); return; }
  idx -= 768;
  if (idx < 768){ initcc[idx]=f2b(gload(initc,idx,f32)); return; }
  idx -= 768;
  if (idx < 256){ qb0c[idx]=f2b(gload(qb0,idx,f32)); return; }
  idx -= 256;
  if (idx < 64){ qb1c[idx]=f2b(gload(qb1,idx,f32)); return; }
  idx -= 64;
  if (idx < 34){ outbc[idx]=f2b(gload(outb,idx,f32)); return; }
}

// gep[part][v][gi] = sum_k emb[v][k] * Wih0[g(part,gi)][256+k]
__global__ __launch_bounds__(256) void prep_ge(
    const void* __restrict__ emb,
    const void* __restrict__ Wih0,
    const int* __restrict__ flags,
    float* __restrict__ gep)
{
  __shared__ float ev[256];
  const int f32 = flags[0];
  const int v = blockIdx.x, tid = threadIdx.x;
  ev[tid] = gload(emb,(long)v*256+tid,f32);
  __syncthreads();
  #pragma unroll
  for (int j=0;j<4;j++){
    const int g = tid*4+j;
    float a = 0.f;
    #pragma unroll 4
    for (int k=0;k<256;k++) a += ev[k]*gload(Wih0,(long)g*512+256+k,f32);
    int pp = (g>>6)&3, gi = ((g>>8)<<6)|(g&63);
    gep[((size_t)pp*34+v)*256+gi] = a;
  }
}

// ---------------------------------------------------------------------------
// key MLP: keyT[n][q][l]  (unchanged)
// ---------------------------------------------------------------------------
__global__ __launch_bounds__(256) void key_mlp(
    const void* __restrict__ seqs,
    const unsigned short* __restrict__ kW0T, const void* __restrict__ kb0,
    const unsigned short* __restrict__ kW1T, const void* __restrict__ kb1,
    const int* __restrict__ flags,
    unsigned short* __restrict__ keyT)
{
  __shared__ float Xt[16*512];
  __shared__ unsigned short Hd[16*512];
  const int f32 = flags[0];
  const int tid = threadIdx.x;
  const int R0 = blockIdx.x*16;
  for (int i=tid;i<8192;i+=256) Xt[i] = gload(seqs,(long)R0*512+i,f32);
  __syncthreads();
  {
    const int j0 = 2*tid;
    float acc0[16], acc1[16];
    #pragma unroll
    for (int r=0;r<16;r++){ acc0[r]=0.f; acc1[r]=0.f; }
    for (int k=0;k<512;k++){
      ushort2 w = *reinterpret_cast<const ushort2*>(kW0T + (size_t)k*512 + j0);
      float w0=b2f(w.x), w1=b2f(w.y);
      #pragma unroll
      for (int r=0;r<16;r++){ float x = Xt[r*512+k]; acc0[r]+=x*w0; acc1[r]+=x*w1; }
    }
    float b0v=gload(kb0,j0,f32), b1v=gload(kb0,j0+1,f32);
    #pragma unroll
    for (int r=0;r<16;r++){
      Hd[r*512+j0]   = f2b(eluf(acc0[r]+b0v));
      Hd[r*512+j0+1] = f2b(eluf(acc1[r]+b1v));
    }
  }
  __syncthreads();
  {
    const int j = tid & 63;
    const int rbase = tid >> 6;
    float acc[4] = {0.f,0.f,0.f,0.f};
    for (int k=0;k<512;k++){
      float w = b2f(kW1T[(size_t)k*64 + j]);
      #pragma unroll
      for (int m=0;m<4;m++) acc[m] += b2f(Hd[(rbase+4*m)*512 + k]) * w;
    }
    float bv = gload(kb1,j,f32);
    #pragma unroll
    for (int m=0;m<4;m++){
      int R = R0 + rbase + 4*m;
      int l = R >> 6, n = R & 63;
      keyT[((size_t)(n*64 + j))*1024 + l] = f2b(acc[m]+bv);
    }
  }
}

// ---------------------------------------------------------------------------
// value MLP: value[n][l][h]  (unchanged)
// ---------------------------------------------------------------------------
__global__ __launch_bounds__(256) void value_mlp(
    const void* __restrict__ seqs,
    const unsigned short* __restrict__ vW0T, const void* __restrict__ vb0,
    const unsigned short* __restrict__ vW1T, const void* __restrict__ vb1,
    const int* __restrict__ flags,
    unsigned short* __restrict__ value)
{
  __shared__ float Xt[16*512];
  __shared__ float Hd[16*256];
  const int f32 = flags[0];
  const int tid = threadIdx.x;
  const int R0 = blockIdx.x*16;
  for (int i=tid;i<8192;i+=256) Xt[i] = gload(seqs,(long)R0*512+i,f32);
  __syncthreads();
  {
    const int j0 = 2*(tid & 127);
    const int rh = tid >> 7;
    float acc0[8], acc1[8];
    #pragma unroll
    for (int r=0;r<8;r++){ acc0[r]=0.f; acc1[r]=0.f; }
    for (int k=0;k<512;k++){
      ushort2 w = *reinterpret_cast<const ushort2*>(vW0T + (size_t)k*256 + j0);
      float w0=b2f(w.x), w1=b2f(w.y);
      #pragma unroll
      for (int r=0;r<8;r++){ float x = Xt[(rh*8+r)*512+k]; acc0[r]+=x*w0; acc1[r]+=x*w1; }
    }
    float b0v=gload(vb0,j0,f32), b1v=gload(vb0,j0+1,f32);
    #pragma unroll
    for (int r=0;r<8;r++){
      Hd[(rh*8+r)*256+j0]   = eluf(acc0[r]+b0v);
      Hd[(rh*8+r)*256+j0+1] = eluf(acc1[r]+b1v);
    }
  }
  __syncthreads();
  {
    const int j = tid;
    float acc[16];
    #pragma unroll
    for (int r=0;r<16;r++) acc[r]=0.f;
    for (int k=0;k<256;k++){
      float w = b2f(vW1T[(size_t)k*256 + j]);
      #pragma unroll
      for (int r=0;r<16;r++) acc[r] += Hd[r*256+k]*w;
    }
    float bv = gload(vb1,j,f32);
    #pragma unroll
    for (int r=0;r<16;r++){
      int R = R0 + r; int l = R>>6, n = R&63;
      value[((size_t)n*1024 + l)*256 + j] = f2b(acc[r]+bv);
    }
  }
}

__global__ __launch_bounds__(256) void zero_hbuf(ull* __restrict__ f){
  int i = blockIdx.x*256 + threadIdx.x;
  if (i < 115200) f[i] = 0;   // tag 0 matches no round (tags start at 1)
}

// ---------------------------------------------------------------------------
// Decode: 256 blocks x 512 threads, 1 block/CU. Block bid = n*4+p so XCD
// (bid%8) hosts a single part -> per-XCD L2 footprint ~2 MB. DO NOT remap
// (r1: FETCH x7, 3x slower). DO NOT widen blocks (r3: 2x slower). DO NOT
// single-acc dot-map the matvec (r5: 4x slower). DO NOT hold weights in a
// lambda-captured ARRAY (r6: scratch spill, VGPR stuck at 128, 20 GB FETCH,
// 3x slower) — r7 uses 32 individually-NAMED uint4 registers, stage B inline.
// r4 evidence: polls find tags in ~1-2 iterations -> time is the block's OWN
// phase pipeline (weight-stream drains at barriers), not exchange latency.
// Mailbox per n (ull): H0[256] H1[256] H2[256] PCTX[4][256] STAT[4][2].
// ---------------------------------------------------------------------------
__global__ __launch_bounds__(512, 1) void speller(
    const unsigned short* __restrict__ keyT,
    const unsigned short* __restrict__ value,
    const unsigned short* __restrict__ Wl0,
    const unsigned short* __restrict__ Wl1,
    const unsigned short* __restrict__ Wl2,
    const unsigned short* __restrict__ qW0v,
    const unsigned short* __restrict__ qW1v,
    const float* __restrict__ bsum_p,
    const float* __restrict__ gep,
    const unsigned short* __restrict__ inithc,
    const unsigned short* __restrict__ initcc,
    const unsigned short* __restrict__ qb0c,
    const unsigned short* __restrict__ qb1c,
    const unsigned short* __restrict__ outWc,
    const unsigned short* __restrict__ outbc,
    const int* __restrict__ labels,
    const int* __restrict__ seq_lens,
    const int* __restrict__ dflags,
    ull* __restrict__ hbw,
    void* __restrict__ out)
{
  extern __shared__ char smem_dyn[];
  unsigned short* vlds = (unsigned short*)smem_dyn;   // [256 l][256 h] quarter, 128 KB

  __shared__ float sacc[4096];
  __shared__ float inc[512];
  __shared__ float garr[256];
  __shared__ float h0[256], h1[256], h2[256], ctx[256];
  __shared__ float cloc[3][64];
  __shared__ float xq[256];
  __shared__ float qv[64];
  __shared__ float earr[256];
  __shared__ float red[16];
  __shared__ float wf[4];
  __shared__ float pcl[256];
  __shared__ float statl[8];

  const int tid = threadIdx.x;
  const int n = blockIdx.x >> 2;     // bid = n*4 + p
  const int p = blockIdx.x & 3;
  const int f32o = dflags[0];
  const int i64 = dflags[1];
  const int slen = i64 ? seq_lens[2*n] : seq_lens[n];

  ull* mb   = hbw + (size_t)n*1800;
  ull* H0w  = mb;            // [256]
  ull* H1w  = mb + 256;      // [256]
  ull* H2w  = mb + 512;      // [256]
  ull* PCw  = mb + 768;      // [4][256]
  ull* STw  = mb + 1792;     // [4][2]

  // preload value quarter into LDS (once)
  {
    const uint4* src = (const uint4*)(value + ((size_t)n*1024 + p*256)*256);
    uint4* dst = (uint4*)vlds;
    for (int i=tid;i<16384;i+=512) dst[i] = src[i];
  }
  if (tid < 256){ h0[tid]=b2f(inithc[tid]); h1[tid]=b2f(inithc[256+tid]); h2[tid]=b2f(inithc[512+tid]); }
  if (tid < 64){
    cloc[0][tid]=b2f(initcc[p*64+tid]);
    cloc[1][tid]=b2f(initcc[256+p*64+tid]);
    cloc[2][tid]=b2f(initcc[512+p*64+tid]);
  }
  const int go8 = tid & 31, ks = tid >> 5;
  // stage-B weights in 32 NAMED uint4 registers (no array -> no scratch).
  const unsigned short* wp1 = Wl1 + (size_t)p*131072 + (size_t)ks*32*256 + go8*8;
  #define LDW(K) const uint4 wb##K = *reinterpret_cast<const uint4*>(wp1 + (size_t)(K)*256);
  LDW(0) LDW(1) LDW(2) LDW(3) LDW(4) LDW(5) LDW(6) LDW(7)
  LDW(8) LDW(9) LDW(10) LDW(11) LDW(12) LDW(13) LDW(14) LDW(15)
  LDW(16) LDW(17) LDW(18) LDW(19) LDW(20) LDW(21) LDW(22) LDW(23)
  LDW(24) LDW(25) LDW(26) LDW(27) LDW(28) LDW(29) LDW(30) LDW(31)
  #undef LDW
  __syncthreads();

  // out projection (rows r = 4*ri + p, + rows 32,33 on parts 0,1). Reads only
  // ctx/h2 (stable from attn of step t until attn/stage-C of t+1) -> runs in
  // stage-A's pre-barrier slot, overlapped with stage-A weight-load latency.
  auto outproj = [&](int t){
    const int ri = tid >> 6, kk = tid & 63;
    const int r = 4*ri + p;
    float acc = 0.f;
    const unsigned short* wr = outWc + (size_t)r*512 + kk;
    #pragma unroll
    for (int s=0;s<4;s++) acc += ctx[s*64+kk]*b2f(wr[s*64]);
    #pragma unroll
    for (int s=0;s<4;s++) acc += h2[s*64+kk]*b2f(wr[256+s*64]);
    #pragma unroll
    for (int off=32; off>0; off>>=1) acc += __shfl_down(acc, off);
    if (kk==0){
      float v = acc + b2f(outbc[r]);
      size_t oi = ((size_t)(t*64+n))*34 + r;
      if (f32o) ((float*)out)[oi]=v; else ((unsigned short*)out)[oi]=f2b(v);
    }
    if (p < 2 && tid < 64){
      const int r2 = 32+p;
      float a2=0.f;
      const unsigned short* wr2 = outWc + (size_t)r2*512 + tid;
      #pragma unroll
      for (int s=0;s<4;s++) a2 += ctx[s*64+tid]*b2f(wr2[s*64]);
      #pragma unroll
      for (int s=0;s<4;s++) a2 += h2[s*64+tid]*b2f(wr2[256+s*64]);
      #pragma unroll
      for (int off=32; off>0; off>>=1) a2 += __shfl_down(a2, off);
      if (tid==0){
        float v = a2 + b2f(outbc[r2]);
        size_t oi = ((size_t)(t*64+n))*34 + r2;
        if (f32o) ((float*)out)[oi]=v; else ((unsigned short*)out)[oi]=f2b(v);
      }
    }
  };

  // Stage-A LSTM: x from inc[512] (LDS, built by attn fold). Own h slice ->
  // mailbox only. tprev>=0: previous step's out-proj in the pre-barrier slot.
  auto lstm_lds = [&](const unsigned short* W, const float* bs, const float* ger,
                      int layer, ull* Hw, unsigned tag, int tprev){
    const unsigned short* wp = W + (size_t)p*131072 + (size_t)ks*32*256 + go8*8;
    const float* xin = inc + ks*32;
    float a0=0.f,a1=0.f,a2=0.f,a3=0.f,a4=0.f,a5=0.f,a6=0.f,a7=0.f;
    #pragma unroll 16
    for (int k=0;k<32;k++){
      float x = xin[k];
      uint4 w = *reinterpret_cast<const uint4*>(wp + (size_t)k*256);
      a0 += x*lo16(w.x); a1 += x*hi16(w.x);
      a2 += x*lo16(w.y); a3 += x*hi16(w.y);
      a4 += x*lo16(w.z); a5 += x*hi16(w.z);
      a6 += x*lo16(w.w); a7 += x*hi16(w.w);
    }
    float* sb = sacc + ks*256 + go8*8;
    sb[0]=a0; sb[1]=a1; sb[2]=a2; sb[3]=a3; sb[4]=a4; sb[5]=a5; sb[6]=a6; sb[7]=a7;
    if (tprev >= 0) outproj(tprev);
    __syncthreads();
    if (tid < 256){
      float s = bs[tid] + (ger ? ger[tid] : 0.f);
      #pragma unroll
      for (int u=0;u<16;u++) s += sacc[u*256+tid];
      garr[tid] = s;
    }
    __syncthreads();
    if (tid < 64){
      __builtin_amdgcn_s_setprio(1);
      float gi=garr[tid], gf=garr[64+tid], gg=garr[128+tid], go=garr[192+tid];
      float cc = sigf(gf)*cloc[layer][tid] + sigf(gi)*tanhf(gg);
      float hh = sigf(go)*tanhf(cc);
      cloc[layer][tid]=cc;
      ast64(Hw + p*64 + tid, pk(hh, tag));
      __builtin_amdgcn_s_setprio(0);
    }
    // no trailing barrier; next phase's sacc writes are safe (reduce done)
  };

  // Fused-poll LSTM, streamed weights (stage C): x-half (waves 0-3) polled
  // per-lane from mailbox Xw and distributed via __shfl; h-half (waves 4-7)
  // from LDS hprev, starts immediately. Polled x written back to xdst[].
  auto lstm_poll = [&](const unsigned short* W, const float* bs,
                       const ull* Xw, unsigned xtag, const float* hprev,
                       float* xdst, int layer, ull* Hw, unsigned tag){
    const int lane = tid & 63, wv = tid >> 6;
    float xv;
    if (wv < 4){
      const ull* wd = Xw + tid;
      ull u = ald64(wd);
      while ((unsigned)(u>>32) != xtag) u = ald64(wd);
      xv = upk(u);
    } else {
      xv = hprev[tid - 256];
    }
    const unsigned short* wp = W + (size_t)p*131072 + (size_t)ks*32*256 + go8*8;
    float a0=0.f,a1=0.f,a2=0.f,a3=0.f,a4=0.f,a5=0.f,a6=0.f,a7=0.f;
    #pragma unroll 16
    for (int k=0;k<32;k++){
      float x = __shfl(xv, (lane & 32) | k);
      uint4 w = *reinterpret_cast<const uint4*>(wp + (size_t)k*256);
      a0 += x*lo16(w.x); a1 += x*hi16(w.x);
      a2 += x*lo16(w.y); a3 += x*hi16(w.y);
      a4 += x*lo16(w.z); a5 += x*hi16(w.z);
      a6 += x*lo16(w.w); a7 += x*hi16(w.w);
    }
    float* sb = sacc + ks*256 + go8*8;
    sb[0]=a0; sb[1]=a1; sb[2]=a2; sb[3]=a3; sb[4]=a4; sb[5]=a5; sb[6]=a6; sb[7]=a7;
    if (wv < 4) xdst[tid] = xv;     // h-full writeback (gather eliminated)
    __syncthreads();
    if (tid < 256){
      float s = bs[tid];
      #pragma unroll
      for (int u=0;u<16;u++) s += sacc[u*256+tid];
      garr[tid] = s;
    }
    __syncthreads();
    if (tid < 64){
      __builtin_amdgcn_s_setprio(1);
      float gi=garr[tid], gf=garr[64+tid], gg=garr[128+tid], go=garr[192+tid];
      float cc = sigf(gf)*cloc[layer][tid] + sigf(gi)*tanhf(gg);
      float hh = sigf(go)*tanhf(cc);
      cloc[layer][tid]=cc;
      ast64(Hw + p*64 + tid, pk(hh, tag));
      __builtin_amdgcn_s_setprio(0);
    }
  };

  // h2 gather: all 256 words polled from mailbox (own slice included).
  auto gather_h2 = [&](unsigned tag){
    if (tid < 256){
      const ull* w = H2w + tid; ull u = ald64(w);
      while ((unsigned)(u>>32) != tag) u = ald64(w);
      h2[tid] = upk(u);
    }
    __syncthreads();
  };

  // attention: replicated q-MLP from full h2 (LDS), own l-quarter scores +
  // softmax partials + partial ctx -> tagged mailbox; exact assembly.
  // Folds next stage-A inc copy: inc = [ctx_new, h0].
  auto attn = [&](unsigned tag){
    { // xq: j=tid&255, kh=tid>>8 -> 16 coalesced uint4 loads (qW0v tiles)
      const int j = tid & 255, kh = tid >> 8;
      const uint4* qp = (const uint4*)qW0v + (size_t)(kh*16)*256 + j;
      float a = 0.f;
      #pragma unroll
      for (int k8=0;k8<16;k8++){
        uint4 w = qp[(size_t)k8*256];
        const float* hb = h2 + kh*128 + k8*8;
        a += hb[0]*lo16(w.x)+hb[1]*hi16(w.x)
           + hb[2]*lo16(w.y)+hb[3]*hi16(w.y)
           + hb[4]*lo16(w.z)+hb[5]*hi16(w.z)
           + hb[6]*lo16(w.w)+hb[7]*hi16(w.w);
      }
      sacc[kh*256 + j] = a;
    }
    __syncthreads();
    if (tid < 256) xq[tid] = eluf(sacc[tid]+sacc[256+tid] + b2f(qb0c[tid]));
    __syncthreads();
    { // qv: qc=tid&63, s=tid>>6 (8 k-strips of 32) -> 2x2 uint4 tile loads
      const int qc = tid & 63, s = tid >> 6;
      const uint4* qp = (const uint4*)qW1v + (size_t)(2*s*64+qc)*2;
      float a = 0.f;
      #pragma unroll
      for (int half=0;half<2;half++){
        const uint4* qph = qp + (size_t)half*64*2;
        #pragma unroll
        for (int u=0;u<2;u++){
          uint4 w = qph[u];
          const float* xb = xq + s*32 + half*16 + u*8;
          a += xb[0]*lo16(w.x)+xb[1]*hi16(w.x)
             + xb[2]*lo16(w.y)+xb[3]*hi16(w.y)
             + xb[4]*lo16(w.z)+xb[5]*hi16(w.z)
             + xb[6]*lo16(w.w)+xb[7]*hi16(w.w);
        }
      }
      sacc[s*64+qc] = a;
    }
    __syncthreads();
    if (tid < 64){
      float s=0.f;
      #pragma unroll
      for (int u=0;u<8;u++) s += sacc[u*64+tid];
      qv[tid] = s + b2f(qb1c[tid]);
    }
    __syncthreads();
    { // scores own l-quarter: l-pairs x 4 q-chunks of 16
      const int lp = tid & 127, qh = tid >> 7;
      float a0=0.f,a1=0.f;
      const unsigned short* kp = keyT + (size_t)n*65536 + (size_t)qh*16*1024 + p*256 + 2*lp;
      #pragma unroll 8
      for (int q=0;q<16;q++){
        ushort2 w = *reinterpret_cast<const ushort2*>(kp + (size_t)q*1024);
        float qq = qv[qh*16+q];
        a0 += qq*b2f(w.x); a1 += qq*b2f(w.y);
      }
      sacc[qh*256+2*lp]=a0; sacc[qh*256+2*lp+1]=a1;
    }
    __syncthreads();
    // wave-shuffle softmax partials
    float pmax, psum;
    {
      float s = -1e30f;
      if (tid < 256){
        s = sacc[tid]+sacc[256+tid]+sacc[512+tid]+sacc[768+tid];
        if (p*256+tid >= slen) s = -1e30f;
      }
      float m = s;
      #pragma unroll
      for (int off=32; off; off>>=1) m = fmaxf(m, __shfl_xor(m, off));
      if ((tid&63)==0) red[tid>>6] = m;
      __syncthreads();
      pmax = fmaxf(fmaxf(red[0],red[1]),fmaxf(red[2],red[3]));
      float e = 0.f;
      if (tid < 256){
        e = (p*256+tid < slen) ? __expf(s - pmax) : 0.f;
        earr[tid] = e;
      }
      float ss = e;
      #pragma unroll
      for (int off=32; off; off>>=1) ss += __shfl_xor(ss, off);
      if ((tid&63)==0) red[8+(tid>>6)] = ss;
      __syncthreads();
      psum = red[8]+red[9]+red[10]+red[11];
    }
    { // partial ctx from LDS value: h-pairs x 4 l-chunks of 64
      const int hp = tid & 127, lq = tid >> 7;
      float a0=0.f,a1=0.f;
      const unsigned short* vp = vlds + (size_t)(lq*64)*256 + 2*hp;
      #pragma unroll 8
      for (int l=0;l<64;l++){
        ushort2 w = *reinterpret_cast<const ushort2*>(vp + (size_t)l*256);
        float e = earr[lq*64+l];
        a0 += e*b2f(w.x); a1 += e*b2f(w.y);
      }
      sacc[lq*256+2*hp]=a0; sacc[lq*256+2*hp+1]=a1;
    }
    __syncthreads();
    if (tid < 256){
      float v = sacc[tid]+sacc[256+tid]+sacc[512+tid]+sacc[768+tid];
      pcl[tid] = v;
      ast64(PCw + p*256 + tid, pk(v, tag));
    }
    if (tid == 0){ ast64(STw + p*2, pk(pmax, tag)); ast64(STw + p*2 + 1, pk(psum, tag)); }
    // stats gather (all 4 parts): own from registers, remote by poll
    if (tid < 8){
      int q = tid >> 1, ix = tid & 1; float v;
      if (q == p) v = ix ? psum : pmax;
      else { const ull* w = STw + q*2 + ix; ull u = ald64(w);
             while ((unsigned)(u>>32) != tag) u = ald64(w);
             v = upk(u); }
      statl[tid] = v;
    }
    __syncthreads();
    if (tid == 0){
      float m0=statl[0], s0=statl[1], m1=statl[2], s1=statl[3];
      float m2=statl[4], s2=statl[5], m3=statl[6], s3=statl[7];
      float M = fmaxf(fmaxf(m0,m1),fmaxf(m2,m3));
      float w0=__expf(m0-M), w1=__expf(m1-M), w2=__expf(m2-M), w3=__expf(m3-M);
      float inv = 1.f/(s0*w0+s1*w1+s2*w2+s3*w3);
      wf[0]=w0*inv; wf[1]=w1*inv; wf[2]=w2*inv; wf[3]=w3*inv;
    }
    __syncthreads();
    if (tid < 256){
      // parallel remote polls: issue all 3 loads before checking any tag
      const int q0=(p+1)&3, q1=(p+2)&3, q2=(p+3)&3;
      const ull* w0 = PCw + q0*256 + tid;
      const ull* w1 = PCw + q1*256 + tid;
      const ull* w2 = PCw + q2*256 + tid;
      ull u0=ald64(w0), u1=ald64(w1), u2=ald64(w2);
      while ((unsigned)(u0>>32) != tag) u0 = ald64(w0);
      while ((unsigned)(u1>>32) != tag) u1 = ald64(w1);
      while ((unsigned)(u2>>32) != tag) u2 = ald64(w2);
      float acc = pcl[tid]*wf[p] + upk(u0)*wf[q0] + upk(u1)*wf[q1] + upk(u2)*wf[q2];
      ctx[tid] = acc;
      inc[tid] = acc;            // stage-A x-half
      inc[256+tid] = h0[tid];    // stage-A h-half (h0 from stage-B writeback)
    }
    __syncthreads();
  };

  attn(1);   // initial prev_ctx from inith[2] (h2 local)

  int lab = i64 ? labels[2*n] : labels[n];
  for (int t=0;t<256;t++){
    const unsigned tb = 4*(unsigned)t;
    const float* ger = gep + ((size_t)p*34+lab)*256;
    int lab_next = 0;
    if (t < 255) lab_next = i64 ? labels[2*((t+1)*64+n)] : labels[(t+1)*64+n];
    // stage A: inc = {ctx, h0_prev} (folded by attn); out-proj(t-1) overlapped
    lstm_lds(Wl0, bsum_p + p*256, ger, 0, H0w, tb+2, t-1);
    // stage B (inline): x = h0_new (fused poll), h = h1_prev; weights wb0..wb31
    {
      const int lane = tid & 63, wv = tid >> 6;
      float xv;
      if (wv < 4){
        const ull* wd = H0w + tid;
        ull u = ald64(wd);
        while ((unsigned)(u>>32) != tb+2) u = ald64(wd);
        xv = upk(u);
      } else {
        xv = h1[tid - 256];
      }
      float a0=0.f,a1=0.f,a2=0.f,a3=0.f,a4=0.f,a5=0.f,a6=0.f,a7=0.f;
      #define BSTEP(K) { float x = __shfl(xv, (lane & 32) | (K)); \
        a0 += x*lo16(wb##K.x); a1 += x*hi16(wb##K.x); \
        a2 += x*lo16(wb##K.y); a3 += x*hi16(wb##K.y); \
        a4 += x*lo16(wb##K.z); a5 += x*hi16(wb##K.z); \
        a6 += x*lo16(wb##K.w); a7 += x*hi16(wb##K.w); }
      BSTEP(0) BSTEP(1) BSTEP(2) BSTEP(3) BSTEP(4) BSTEP(5) BSTEP(6) BSTEP(7)
      BSTEP(8) BSTEP(9) BSTEP(10) BSTEP(11) BSTEP(12) BSTEP(13) BSTEP(14) BSTEP(15)
      BSTEP(16) BSTEP(17) BSTEP(18) BSTEP(19) BSTEP(20) BSTEP(21) BSTEP(22) BSTEP(23)
      BSTEP(24) BSTEP(25) BSTEP(26) BSTEP(27) BSTEP(28) BSTEP(29) BSTEP(30) BSTEP(31)
      #undef BSTEP
      float* sb = sacc + ks*256 + go8*8;
      sb[0]=a0; sb[1]=a1; sb[2]=a2; sb[3]=a3; sb[4]=a4; sb[5]=a5; sb[6]=a6; sb[7]=a7;
      if (wv < 4) h0[tid] = xv;     // h0 writeback (gather eliminated)
      __syncthreads();
      if (tid < 256){
        float s = bsum_p[1024 + p*256 + tid];
        #pragma unroll
        for (int u=0;u<16;u++) s += sacc[u*256+tid];
        garr[tid] = s;
      }
      __syncthreads();
      if (tid < 64){
        __builtin_amdgcn_s_setprio(1);
        float gi=garr[tid], gf=garr[64+tid], gg=garr[128+tid], go=garr[192+tid];
        float cc = sigf(gf)*cloc[1][tid] + sigf(gi)*tanhf(gg);
        float hh = sigf(go)*tanhf(cc);
        cloc[1][tid]=cc;
        ast64(H1w + p*64 + tid, pk(hh, tb+3));
        __builtin_amdgcn_s_setprio(0);
      }
    }
    // stage C: x = h1_new (fused poll), h = h2_prev; h1[] updated
    lstm_poll(Wl2, bsum_p + 2048 + p*256, H1w, tb+3, h2, h1, 2, H2w, tb+4);
    // h2 full for attn/out-proj
    gather_h2(tb+4);
    // stage D: attention (folds inc = {ctx_new, h0} for next stage A)
    attn(tb+5);
    lab = lab_next;
  }
  outproj(255);
}

extern "C" void kernel_launch(void* const* d_in, const int* in_sizes, int n_in,
                              void* d_out, int out_size, void* d_ws, size_t ws_size,
                              hipStream_t stream) {
  const void* seqs  = d_in[0];
  const int* seq_lens = (const int*)d_in[1];
  const int* labels   = (const int*)d_in[2];
  const void* emb   = d_in[3];
  const void* inith = d_in[4];
  const void* initc = d_in[5];
  const void* Wih0 = d_in[6];  const void* Whh0 = d_in[7];
  const void* bih0 = d_in[8];  const void* bhh0 = d_in[9];
  const void* Wih1 = d_in[10]; const void* Whh1 = d_in[11];
  const void* bih1 = d_in[12]; const void* bhh1 = d_in[13];
  const void* Wih2 = d_in[14]; const void* Whh2 = d_in[15];
  const void* bih2 = d_in[16]; const void* bhh2 = d_in[17];
  const void* qW0 = d_in[18];  const void* qb0 = d_in[19];
  const void* qW1 = d_in[20];  const void* qb1 = d_in[21];
  const void* kW0 = d_in[22];  const void* kb0 = d_in[23];
  const void* kW1 = d_in[24];  const void* kb1 = d_in[25];
  const void* vW0 = d_in[26];  const void* vb0 = d_in[27];
  const void* vW1 = d_in[28];  const void* vb1 = d_in[29];
  const void* outW = d_in[30]; const void* outb = d_in[31];

  char* ws = (char*)d_ws;
  unsigned short* keyT  = (unsigned short*)(ws);             //  8,388,608 B  [64][64][1024]
  unsigned short* value = (unsigned short*)(ws + 8388608);   // 33,554,432 B  [64][1024][256]
  unsigned short* Wl0   = (unsigned short*)(ws + 41943040);  //  1,048,576 B  [4][512][256]
  unsigned short* Wl1   = (unsigned short*)(ws + 42991616);
  unsigned short* Wl2   = (unsigned short*)(ws + 44040192);
  unsigned short* kW0T  = (unsigned short*)(ws + 45088768);  //    524,288 B (prep-only)
  unsigned short* kW1T  = (unsigned short*)(ws + 45613056);  //     65,536 B (prep-only)
  unsigned short* vW0T  = (unsigned short*)(ws + 45678592);  //    262,144 B (prep-only)
  unsigned short* vW1T  = (unsigned short*)(ws + 45940736);  //    131,072 B (prep-only)
  unsigned short* qW0v  = (unsigned short*)(ws + 46071808);  //    131,072 B
  unsigned short* qW1v  = (unsigned short*)(ws + 46202880);  //     32,768 B
  float*          bsum  = (float*)(ws + 46235648);           //     12,288 B  [3][4][256]
  float*          gep   = (float*)(ws + 46247936);           //    139,264 B  [4][34][256]
  unsigned short* outWc = (unsigned short*)(ws + 46387200);  //     34,816 B
  unsigned short* inithc= (unsigned short*)(ws + 46422016);  //      1,536 B
  unsigned short* initcc= (unsigned short*)(ws + 46423552);  //      1,536 B
  unsigned short* qb0c  = (unsigned short*)(ws + 46425088);  //        512 B
  unsigned short* qb1c  = (unsigned short*)(ws + 46425600);  //        128 B
  unsigned short* outbc = (unsigned short*)(ws + 46425728);  //        128 B
  int*            dflags= (int*)(ws + 46425856);             //         16 B
  // tagged mailbox overlaps kW0T..vW1T (all consumed before speller starts):
  ull* hbw = (ull*)(ws + 45088768);                          //    921,600 B  [64][1800] ull

  sniff<<<dim3(1), dim3(64), 0, stream>>>(seqs, seq_lens, dflags);
  prep_transpose<<<dim3(8472), dim3(256), 0, stream>>>(
      Wih0,Whh0,Wih1,Whh1,Wih2,Whh2, kW0,kW1,vW0,vW1,qW0,qW1,
      bih0,bhh0,bih1,bhh1,bih2,bhh2,
      outW,inith,initc,qb0,qb1,outb, dflags,
      Wl0,Wl1,Wl2,kW0T,kW1T,vW0T,vW1T,qW0v,qW1v,bsum,
      outWc,inithc,initcc,qb0c,qb1c,outbc);
  prep_ge<<<dim3(34), dim3(256), 0, stream>>>(emb, Wih0, dflags, gep);
  key_mlp<<<dim3(4096), dim3(256), 0, stream>>>(seqs, kW0T, kb0, kW1T, kb1, dflags, keyT);
  value_mlp<<<dim3(4096), dim3(256), 0, stream>>>(seqs, vW0T, vb0, vW1T, vb1, dflags, value);
  zero_hbuf<<<dim3(450), dim3(256), 0, stream>>>(hbw);
  hipFuncSetAttribute((const void*)speller, hipFuncAttributeMaxDynamicSharedMemorySize, 131072);
  speller<<<dim3(256), dim3(512), 131072, stream>>>(
      keyT, value, Wl0, Wl1, Wl2, qW0v, qW1v, bsum, gep,
      inithc, initcc, qb0c, qb1c, outWc, outbc, labels, seq_lens, dflags,
      hbw, d_out);
}

// Round 8
// 8122.001 us; speedup vs baseline: 3.4626x; 2.4251x over previous
//
#include <hip/hip_runtime.h>
#include <cstddef>

#define DEV static __device__ __forceinline__
typedef unsigned long long ull;

DEV float b2f(unsigned short u){ unsigned int i=((unsigned int)u)<<16; float f; __builtin_memcpy(&f,&i,4); return f; }
DEV float lo16(unsigned int u){ unsigned int i=u<<16; float f; __builtin_memcpy(&f,&i,4); return f; }
DEV float hi16(unsigned int u){ unsigned int i=u&0xffff0000u; float f; __builtin_memcpy(&f,&i,4); return f; }
DEV unsigned short f2b(float f){ unsigned int i; __builtin_memcpy(&i,&f,4); unsigned int r=(i+0x7fffu+((i>>16)&1u))>>16; return (unsigned short)r; }
DEV float sigf(float x){ return 1.f/(1.f+__expf(-x)); }
DEV float eluf(float x){ return x>0.f ? x : (__expf(x)-1.f); }
DEV float gload(const void* p, long i, int f32){
  return f32 ? ((const float*)p)[i] : b2f(((const unsigned short*)p)[i]);
}
// tagged-word mailbox: {tag<<32 | f32 bits}, relaxed agent atomics (LLC point).
DEV ull pk(float f, unsigned tag){ unsigned b; __builtin_memcpy(&b,&f,4); return ((ull)tag<<32)|b; }
DEV float upk(ull u){ unsigned b=(unsigned)u; float f; __builtin_memcpy(&f,&b,4); return f; }
DEV void ast64(ull* p, ull v){ __hip_atomic_store(p, v, __ATOMIC_RELAXED, __HIP_MEMORY_SCOPE_AGENT); }
DEV ull ald64(const ull* p){ return __hip_atomic_load(p, __ATOMIC_RELAXED, __HIP_MEMORY_SCOPE_AGENT); }

// ---------------------------------------------------------------------------
// Sniff input dtypes. flags[0]=1 if floats are f32; flags[1]=1 if ints are i64.
// ---------------------------------------------------------------------------
__global__ __launch_bounds__(64) void sniff(const void* __restrict__ seqs,
                                            const void* __restrict__ seq_lens,
                                            int* __restrict__ flags)
{
  __shared__ int cnt;
  if (threadIdx.x==0) cnt=0;
  __syncthreads();
  const unsigned short* u = (const unsigned short*)seqs;
  int sane=0;
  for (int i=threadIdx.x;i<1024;i+=64){
    int e = (u[i]>>7)&0xFF;
    if (e>=0x70 && e<=0x8F) sane++;
  }
  atomicAdd(&cnt, sane);
  __syncthreads();
  if (threadIdx.x==0){
    flags[0] = (cnt < 820) ? 1 : 0;
    const int* s = (const int*)seq_lens;
    flags[1] = ((s[1]|s[3]|s[5]|s[7])==0) ? 1 : 0;
  }
}

// ---------------------------------------------------------------------------
// Prep: part-sliced bf16 weights (r4-proven layout).
// Wl[l][part][k][gi]: gi in [0,256): type=gi>>6, jj=gi&63,
// g = type*256 + part*64 + jj.  k<256 -> ih (ctx/h_in), k>=256 -> hh.
// qW0v: [k8][j][kk8] tiles.  qW1v: [s16][qc][kk16] tiles.
// ---------------------------------------------------------------------------
__global__ __launch_bounds__(256) void prep_transpose(
    const void* __restrict__ Wih0, const void* __restrict__ Whh0,
    const void* __restrict__ Wih1, const void* __restrict__ Whh1,
    const void* __restrict__ Wih2, const void* __restrict__ Whh2,
    const void* __restrict__ kW0,  const void* __restrict__ kW1,
    const void* __restrict__ vW0,  const void* __restrict__ vW1,
    const void* __restrict__ qW0,  const void* __restrict__ qW1,
    const void* __restrict__ bih0, const void* __restrict__ bhh0,
    const void* __restrict__ bih1, const void* __restrict__ bhh1,
    const void* __restrict__ bih2, const void* __restrict__ bhh2,
    const void* __restrict__ outW, const void* __restrict__ inith,
    const void* __restrict__ initc, const void* __restrict__ qb0,
    const void* __restrict__ qb1,  const void* __restrict__ outb,
    const int* __restrict__ flags,
    unsigned short* __restrict__ Wl0, unsigned short* __restrict__ Wl1,
    unsigned short* __restrict__ Wl2,
    unsigned short* __restrict__ kW0T, unsigned short* __restrict__ kW1T,
    unsigned short* __restrict__ vW0T, unsigned short* __restrict__ vW1T,
    unsigned short* __restrict__ qW0v, unsigned short* __restrict__ qW1v,
    float* __restrict__ bsum,
    unsigned short* __restrict__ outWc, unsigned short* __restrict__ inithc,
    unsigned short* __restrict__ initcc, unsigned short* __restrict__ qb0c,
    unsigned short* __restrict__ qb1c,  unsigned short* __restrict__ outbc)
{
  const int f32 = flags[0];
  int idx = blockIdx.x*256 + threadIdx.x;
  if (idx < 524288){ int r=idx&131071, k=r>>8, gi=r&255;
    int g = ((gi>>6)<<8) + ((idx>>17)<<6) + (gi&63);
    Wl0[idx] = f2b((k<256)? gload(Wih0,(long)g*512+k,f32) : gload(Whh0,(long)g*256+(k-256),f32)); return; }
  idx -= 524288;
  if (idx < 524288){ int r=idx&131071, k=r>>8, gi=r&255;
    int g = ((gi>>6)<<8) + ((idx>>17)<<6) + (gi&63);
    Wl1[idx] = f2b((k<256)? gload(Wih1,(long)g*256+k,f32) : gload(Whh1,(long)g*256+(k-256),f32)); return; }
  idx -= 524288;
  if (idx < 524288){ int r=idx&131071, k=r>>8, gi=r&255;
    int g = ((gi>>6)<<8) + ((idx>>17)<<6) + (gi&63);
    Wl2[idx] = f2b((k<256)? gload(Wih2,(long)g*256+k,f32) : gload(Whh2,(long)g*256+(k-256),f32)); return; }
  idx -= 524288;
  if (idx < 262144){ int k=idx>>9, j=idx&511; kW0T[idx]=f2b(gload(kW0,(long)j*512+k,f32)); return; }
  idx -= 262144;
  if (idx < 32768){ int k=idx>>6, j=idx&63; kW1T[idx]=f2b(gload(kW1,(long)j*512+k,f32)); return; }
  idx -= 32768;
  if (idx < 131072){ int k=idx>>8, j=idx&255; vW0T[idx]=f2b(gload(vW0,(long)j*512+k,f32)); return; }
  idx -= 131072;
  if (idx < 65536){ int k=idx>>8, j=idx&255; vW1T[idx]=f2b(gload(vW1,(long)j*256+k,f32)); return; }
  idx -= 65536;
  if (idx < 65536){ // qW0v[(k8*256 + j)*8 + kk] = qW0[j][k8*8+kk]
    int k8=idx>>11, j=(idx>>3)&255, kk=idx&7; int k=k8*8+kk;
    qW0v[idx]=f2b(gload(qW0,(long)j*256+k,f32)); return; }
  idx -= 65536;
  if (idx < 16384){ // qW1v[(s*64 + qc)*16 + kk] = qW1[qc][s*16+kk]
    int s=idx>>10, qc=(idx>>4)&63, kk=idx&15; int k=s*16+kk;
    qW1v[idx]=f2b(gload(qW1,(long)qc*256+k,f32)); return; }
  idx -= 16384;
  if (idx < 3072){ int l=idx>>10, r=idx&1023, pp=r>>8, gi=r&255;
    int g = ((gi>>6)<<8) + (pp<<6) + (gi&63);
    const void* bi = (l==0)?bih0:((l==1)?bih1:bih2);
    const void* bh = (l==0)?bhh0:((l==1)?bhh1:bhh2);
    bsum[idx] = gload(bi,g,f32)+gload(bh,g,f32); return; }
  idx -= 3072;
  if (idx < 17408){ outWc[idx]=f2b(gload(outW,idx,f32)); return; }
  idx -= 17408;
  if (idx < 768){ inithc[idx]=f2b(gload(inith,idx,f32)); return; }
  idx -= 768;
  if (idx < 768){ initcc[idx]=f2b(gload(initc,idx,f32)); return; }
  idx -= 768;
  if (idx < 256){ qb0c[idx]=f2b(gload(qb0,idx,f32)); return; }
  idx -= 256;
  if (idx < 64){ qb1c[idx]=f2b(gload(qb1,idx,f32)); return; }
  idx -= 64;
  if (idx < 34){ outbc[idx]=f2b(gload(outb,idx,f32)); return; }
}

// gep[part][v][gi] = sum_k emb[v][k] * Wih0[g(part,gi)][256+k]
__global__ __launch_bounds__(256) void prep_ge(
    const void* __restrict__ emb,
    const void* __restrict__ Wih0,
    const int* __restrict__ flags,
    float* __restrict__ gep)
{
  __shared__ float ev[256];
  const int f32 = flags[0];
  const int v = blockIdx.x, tid = threadIdx.x;
  ev[tid] = gload(emb,(long)v*256+tid,f32);
  __syncthreads();
  #pragma unroll
  for (int j=0;j<4;j++){
    const int g = tid*4+j;
    float a = 0.f;
    #pragma unroll 4
    for (int k=0;k<256;k++) a += ev[k]*gload(Wih0,(long)g*512+256+k,f32);
    int pp = (g>>6)&3, gi = ((g>>8)<<6)|(g&63);
    gep[((size_t)pp*34+v)*256+gi] = a;
  }
}

// ---------------------------------------------------------------------------
// key MLP: keyT[n][q][l]  (unchanged)
// ---------------------------------------------------------------------------
__global__ __launch_bounds__(256) void key_mlp(
    const void* __restrict__ seqs,
    const unsigned short* __restrict__ kW0T, const void* __restrict__ kb0,
    const unsigned short* __restrict__ kW1T, const void* __restrict__ kb1,
    const int* __restrict__ flags,
    unsigned short* __restrict__ keyT)
{
  __shared__ float Xt[16*512];
  __shared__ unsigned short Hd[16*512];
  const int f32 = flags[0];
  const int tid = threadIdx.x;
  const int R0 = blockIdx.x*16;
  for (int i=tid;i<8192;i+=256) Xt[i] = gload(seqs,(long)R0*512+i,f32);
  __syncthreads();
  {
    const int j0 = 2*tid;
    float acc0[16], acc1[16];
    #pragma unroll
    for (int r=0;r<16;r++){ acc0[r]=0.f; acc1[r]=0.f; }
    for (int k=0;k<512;k++){
      ushort2 w = *reinterpret_cast<const ushort2*>(kW0T + (size_t)k*512 + j0);
      float w0=b2f(w.x), w1=b2f(w.y);
      #pragma unroll
      for (int r=0;r<16;r++){ float x = Xt[r*512+k]; acc0[r]+=x*w0; acc1[r]+=x*w1; }
    }
    float b0v=gload(kb0,j0,f32), b1v=gload(kb0,j0+1,f32);
    #pragma unroll
    for (int r=0;r<16;r++){
      Hd[r*512+j0]   = f2b(eluf(acc0[r]+b0v));
      Hd[r*512+j0+1] = f2b(eluf(acc1[r]+b1v));
    }
  }
  __syncthreads();
  {
    const int j = tid & 63;
    const int rbase = tid >> 6;
    float acc[4] = {0.f,0.f,0.f,0.f};
    for (int k=0;k<512;k++){
      float w = b2f(kW1T[(size_t)k*64 + j]);
      #pragma unroll
      for (int m=0;m<4;m++) acc[m] += b2f(Hd[(rbase+4*m)*512 + k]) * w;
    }
    float bv = gload(kb1,j,f32);
    #pragma unroll
    for (int m=0;m<4;m++){
      int R = R0 + rbase + 4*m;
      int l = R >> 6, n = R & 63;
      keyT[((size_t)(n*64 + j))*1024 + l] = f2b(acc[m]+bv);
    }
  }
}

// ---------------------------------------------------------------------------
// value MLP: value[n][l][h]  (unchanged)
// ---------------------------------------------------------------------------
__global__ __launch_bounds__(256) void value_mlp(
    const void* __restrict__ seqs,
    const unsigned short* __restrict__ vW0T, const void* __restrict__ vb0,
    const unsigned short* __restrict__ vW1T, const void* __restrict__ vb1,
    const int* __restrict__ flags,
    unsigned short* __restrict__ value)
{
  __shared__ float Xt[16*512];
  __shared__ float Hd[16*256];
  const int f32 = flags[0];
  const int tid = threadIdx.x;
  const int R0 = blockIdx.x*16;
  for (int i=tid;i<8192;i+=256) Xt[i] = gload(seqs,(long)R0*512+i,f32);
  __syncthreads();
  {
    const int j0 = 2*(tid & 127);
    const int rh = tid >> 7;
    float acc0[8], acc1[8];
    #pragma unroll
    for (int r=0;r<8;r++){ acc0[r]=0.f; acc1[r]=0.f; }
    for (int k=0;k<512;k++){
      ushort2 w = *reinterpret_cast<const ushort2*>(vW0T + (size_t)k*256 + j0);
      float w0=b2f(w.x), w1=b2f(w.y);
      #pragma unroll
      for (int r=0;r<8;r++){ float x = Xt[(rh*8+r)*512+k]; acc0[r]+=x*w0; acc1[r]+=x*w1; }
    }
    float b0v=gload(vb0,j0,f32), b1v=gload(vb0,j0+1,f32);
    #pragma unroll
    for (int r=0;r<8;r++){
      Hd[(rh*8+r)*256+j0]   = eluf(acc0[r]+b0v);
      Hd[(rh*8+r)*256+j0+1] = eluf(acc1[r]+b1v);
    }
  }
  __syncthreads();
  {
    const int j = tid;
    float acc[16];
    #pragma unroll
    for (int r=0;r<16;r++) acc[r]=0.f;
    for (int k=0;k<256;k++){
      float w = b2f(vW1T[(size_t)k*256 + j]);
      #pragma unroll
      for (int r=0;r<16;r++) acc[r] += Hd[r*256+k]*w;
    }
    float bv = gload(vb1,j,f32);
    #pragma unroll
    for (int r=0;r<16;r++){
      int R = R0 + r; int l = R>>6, n = R&63;
      value[((size_t)n*1024 + l)*256 + j] = f2b(acc[r]+bv);
    }
  }
}

__global__ __launch_bounds__(256) void zero_hbuf(ull* __restrict__ f){
  int i = blockIdx.x*256 + threadIdx.x;
  if (i < 115200) f[i] = 0;   // tag 0 matches no round (tags start at 1)
}

// ---------------------------------------------------------------------------
// Decode: 256 blocks x 512 threads, 1 block/CU. Block bid = n*4+p so XCD
// (bid%8) hosts a single part -> per-XCD L2 footprint ~2 MB. Hard-won rules:
// DO NOT remap blocks (r1: FETCH x7, 3x slower). DO NOT widen blocks (r3: 2x
// slower). DO NOT single-acc dot-map the matvec (r5: 4x slower). DO NOT try
// register-resident weights (r6 array + r7 named-regs BOTH spill to scratch;
// allocator pins this kernel at 128 VGPR; tell = VGPR_Count stuck at 128 +
// FETCH ~20 GB). Polls find tags in ~1-2 iterations (r4) -> time is the
// block's own phase pipeline; FETCH tracks producer lag, not exchange cost.
// r8 = r4 + out-proj hoisted into stage-A's pre-barrier slot + label
// prefetch (both verified correct in r6/r7, isolated here).
// Mailbox per n (ull): H0[256] H1[256] H2[256] PCTX[4][256] STAT[4][2].
// ---------------------------------------------------------------------------
__global__ __launch_bounds__(512, 1) void speller(
    const unsigned short* __restrict__ keyT,
    const unsigned short* __restrict__ value,
    const unsigned short* __restrict__ Wl0,
    const unsigned short* __restrict__ Wl1,
    const unsigned short* __restrict__ Wl2,
    const unsigned short* __restrict__ qW0v,
    const unsigned short* __restrict__ qW1v,
    const float* __restrict__ bsum_p,
    const float* __restrict__ gep,
    const unsigned short* __restrict__ inithc,
    const unsigned short* __restrict__ initcc,
    const unsigned short* __restrict__ qb0c,
    const unsigned short* __restrict__ qb1c,
    const unsigned short* __restrict__ outWc,
    const unsigned short* __restrict__ outbc,
    const int* __restrict__ labels,
    const int* __restrict__ seq_lens,
    const int* __restrict__ dflags,
    ull* __restrict__ hbw,
    void* __restrict__ out)
{
  extern __shared__ char smem_dyn[];
  unsigned short* vlds = (unsigned short*)smem_dyn;   // [256 l][256 h] quarter, 128 KB

  __shared__ float sacc[4096];
  __shared__ float inc[512];
  __shared__ float garr[256];
  __shared__ float h0[256], h1[256], h2[256], ctx[256];
  __shared__ float cloc[3][64];
  __shared__ float xq[256];
  __shared__ float qv[64];
  __shared__ float earr[256];
  __shared__ float red[16];
  __shared__ float wf[4];
  __shared__ float pcl[256];
  __shared__ float statl[8];

  const int tid = threadIdx.x;
  const int n = blockIdx.x >> 2;     // bid = n*4 + p
  const int p = blockIdx.x & 3;
  const int f32o = dflags[0];
  const int i64 = dflags[1];
  const int slen = i64 ? seq_lens[2*n] : seq_lens[n];

  ull* mb   = hbw + (size_t)n*1800;
  ull* H0w  = mb;            // [256]
  ull* H1w  = mb + 256;      // [256]
  ull* H2w  = mb + 512;      // [256]
  ull* PCw  = mb + 768;      // [4][256]
  ull* STw  = mb + 1792;     // [4][2]

  // preload value quarter into LDS (once)
  {
    const uint4* src = (const uint4*)(value + ((size_t)n*1024 + p*256)*256);
    uint4* dst = (uint4*)vlds;
    for (int i=tid;i<16384;i+=512) dst[i] = src[i];
  }
  if (tid < 256){ h0[tid]=b2f(inithc[tid]); h1[tid]=b2f(inithc[256+tid]); h2[tid]=b2f(inithc[512+tid]); }
  if (tid < 64){
    cloc[0][tid]=b2f(initcc[p*64+tid]);
    cloc[1][tid]=b2f(initcc[256+p*64+tid]);
    cloc[2][tid]=b2f(initcc[512+p*64+tid]);
  }
  __syncthreads();

  const int go8 = tid & 31, ks = tid >> 5;

  // out projection (rows r = 4*ri + p, + rows 32,33 on parts 0,1). Reads only
  // ctx/h2 of the PREVIOUS step (stable until gather_h2/attn later in this
  // step; barriers in stages A/B/C separate the read from the next write).
  // Runs inside stage-A's pre-barrier slot, overlapped with the stage-A
  // weight-load latency.
  auto outproj = [&](int t){
    const int ri = tid >> 6, kk = tid & 63;
    const int r = 4*ri + p;
    float acc = 0.f;
    const unsigned short* wr = outWc + (size_t)r*512 + kk;
    #pragma unroll
    for (int s=0;s<4;s++) acc += ctx[s*64+kk]*b2f(wr[s*64]);
    #pragma unroll
    for (int s=0;s<4;s++) acc += h2[s*64+kk]*b2f(wr[256+s*64]);
    #pragma unroll
    for (int off=32; off>0; off>>=1) acc += __shfl_down(acc, off);
    if (kk==0){
      float v = acc + b2f(outbc[r]);
      size_t oi = ((size_t)(t*64+n))*34 + r;
      if (f32o) ((float*)out)[oi]=v; else ((unsigned short*)out)[oi]=f2b(v);
    }
    if (p < 2 && tid < 64){
      const int r2 = 32+p;
      float a2=0.f;
      const unsigned short* wr2 = outWc + (size_t)r2*512 + tid;
      #pragma unroll
      for (int s=0;s<4;s++) a2 += ctx[s*64+tid]*b2f(wr2[s*64]);
      #pragma unroll
      for (int s=0;s<4;s++) a2 += h2[s*64+tid]*b2f(wr2[256+s*64]);
      #pragma unroll
      for (int off=32; off>0; off>>=1) a2 += __shfl_down(a2, off);
      if (tid==0){
        float v = a2 + b2f(outbc[r2]);
        size_t oi = ((size_t)(t*64+n))*34 + r2;
        if (f32o) ((float*)out)[oi]=v; else ((unsigned short*)out)[oi]=f2b(v);
      }
    }
  };

  // Stage-A LSTM: x from inc[512] (LDS, built by attn fold). Own h slice ->
  // mailbox only. tprev>=0: previous step's out-proj in the pre-barrier slot.
  auto lstm_lds = [&](const unsigned short* W, const float* bs, const float* ger,
                      int layer, ull* Hw, unsigned tag, int tprev){
    const unsigned short* wp = W + (size_t)p*131072 + (size_t)ks*32*256 + go8*8;
    const float* xin = inc + ks*32;
    float a0=0.f,a1=0.f,a2=0.f,a3=0.f,a4=0.f,a5=0.f,a6=0.f,a7=0.f;
    #pragma unroll 16
    for (int k=0;k<32;k++){
      float x = xin[k];
      uint4 w = *reinterpret_cast<const uint4*>(wp + (size_t)k*256);
      a0 += x*lo16(w.x); a1 += x*hi16(w.x);
      a2 += x*lo16(w.y); a3 += x*hi16(w.y);
      a4 += x*lo16(w.z); a5 += x*hi16(w.z);
      a6 += x*lo16(w.w); a7 += x*hi16(w.w);
    }
    float* sb = sacc + ks*256 + go8*8;
    sb[0]=a0; sb[1]=a1; sb[2]=a2; sb[3]=a3; sb[4]=a4; sb[5]=a5; sb[6]=a6; sb[7]=a7;
    if (tprev >= 0) outproj(tprev);
    __syncthreads();
    if (tid < 256){
      float s = bs[tid] + (ger ? ger[tid] : 0.f);
      #pragma unroll
      for (int u=0;u<16;u++) s += sacc[u*256+tid];
      garr[tid] = s;
    }
    __syncthreads();
    if (tid < 64){
      __builtin_amdgcn_s_setprio(1);
      float gi=garr[tid], gf=garr[64+tid], gg=garr[128+tid], go=garr[192+tid];
      float cc = sigf(gf)*cloc[layer][tid] + sigf(gi)*tanhf(gg);
      float hh = sigf(go)*tanhf(cc);
      cloc[layer][tid]=cc;
      ast64(Hw + p*64 + tid, pk(hh, tag));
      __builtin_amdgcn_s_setprio(0);
    }
    // no trailing barrier; next phase's sacc writes are safe (reduce done)
  };

  // Fused-poll LSTM, streamed weights (stages B, C): x-half (waves 0-3)
  // polled per-lane from mailbox Xw and distributed via __shfl; h-half
  // (waves 4-7) from LDS hprev, starts immediately. Polled x -> xdst[].
  auto lstm_poll = [&](const unsigned short* W, const float* bs,
                       const ull* Xw, unsigned xtag, const float* hprev,
                       float* xdst, int layer, ull* Hw, unsigned tag){
    const int lane = tid & 63, wv = tid >> 6;
    float xv;
    if (wv < 4){
      const ull* wd = Xw + tid;
      ull u = ald64(wd);
      while ((unsigned)(u>>32) != xtag) u = ald64(wd);
      xv = upk(u);
    } else {
      xv = hprev[tid - 256];
    }
    const unsigned short* wp = W + (size_t)p*131072 + (size_t)ks*32*256 + go8*8;
    float a0=0.f,a1=0.f,a2=0.f,a3=0.f,a4=0.f,a5=0.f,a6=0.f,a7=0.f;
    #pragma unroll 16
    for (int k=0;k<32;k++){
      float x = __shfl(xv, (lane & 32) | k);
      uint4 w = *reinterpret_cast<const uint4*>(wp + (size_t)k*256);
      a0 += x*lo16(w.x); a1 += x*hi16(w.x);
      a2 += x*lo16(w.y); a3 += x*hi16(w.y);
      a4 += x*lo16(w.z); a5 += x*hi16(w.z);
      a6 += x*lo16(w.w); a7 += x*hi16(w.w);
    }
    float* sb = sacc + ks*256 + go8*8;
    sb[0]=a0; sb[1]=a1; sb[2]=a2; sb[3]=a3; sb[4]=a4; sb[5]=a5; sb[6]=a6; sb[7]=a7;
    if (wv < 4) xdst[tid] = xv;     // h-full writeback (gather eliminated)
    __syncthreads();
    if (tid < 256){
      float s = bs[tid];
      #pragma unroll
      for (int u=0;u<16;u++) s += sacc[u*256+tid];
      garr[tid] = s;
    }
    __syncthreads();
    if (tid < 64){
      __builtin_amdgcn_s_setprio(1);
      float gi=garr[tid], gf=garr[64+tid], gg=garr[128+tid], go=garr[192+tid];
      float cc = sigf(gf)*cloc[layer][tid] + sigf(gi)*tanhf(gg);
      float hh = sigf(go)*tanhf(cc);
      cloc[layer][tid]=cc;
      ast64(Hw + p*64 + tid, pk(hh, tag));
      __builtin_amdgcn_s_setprio(0);
    }
  };

  // h2 gather: all 256 words polled from mailbox (own slice included).
  // No opening barrier needed: prior readers of h2[] finished before the
  // stage-C matvec barrier.
  auto gather_h2 = [&](unsigned tag){
    if (tid < 256){
      const ull* w = H2w + tid; ull u = ald64(w);
      while ((unsigned)(u>>32) != tag) u = ald64(w);
      h2[tid] = upk(u);
    }
    __syncthreads();
  };

  // attention: replicated q-MLP from full h2 (LDS), own l-quarter scores +
  // softmax partials + partial ctx -> tagged mailbox; exact assembly.
  // Folds next stage-A inc copy: inc = [ctx_new, h0].
  auto attn = [&](unsigned tag){
    { // xq: j=tid&255, kh=tid>>8 -> 16 coalesced uint4 loads (qW0v tiles)
      const int j = tid & 255, kh = tid >> 8;
      const uint4* qp = (const uint4*)qW0v + (size_t)(kh*16)*256 + j;
      float a = 0.f;
      #pragma unroll
      for (int k8=0;k8<16;k8++){
        uint4 w = qp[(size_t)k8*256];
        const float* hb = h2 + kh*128 + k8*8;
        a += hb[0]*lo16(w.x)+hb[1]*hi16(w.x)
           + hb[2]*lo16(w.y)+hb[3]*hi16(w.y)
           + hb[4]*lo16(w.z)+hb[5]*hi16(w.z)
           + hb[6]*lo16(w.w)+hb[7]*hi16(w.w);
      }
      sacc[kh*256 + j] = a;
    }
    __syncthreads();
    if (tid < 256) xq[tid] = eluf(sacc[tid]+sacc[256+tid] + b2f(qb0c[tid]));
    __syncthreads();
    { // qv: qc=tid&63, s=tid>>6 (8 k-strips of 32) -> 2x2 uint4 tile loads
      const int qc = tid & 63, s = tid >> 6;
      const uint4* qp = (const uint4*)qW1v + (size_t)(2*s*64+qc)*2;
      float a = 0.f;
      #pragma unroll
      for (int half=0;half<2;half++){
        const uint4* qph = qp + (size_t)half*64*2;
        #pragma unroll
        for (int u=0;u<2;u++){
          uint4 w = qph[u];
          const float* xb = xq + s*32 + half*16 + u*8;
          a += xb[0]*lo16(w.x)+xb[1]*hi16(w.x)
             + xb[2]*lo16(w.y)+xb[3]*hi16(w.y)
             + xb[4]*lo16(w.z)+xb[5]*hi16(w.z)
             + xb[6]*lo16(w.w)+xb[7]*hi16(w.w);
        }
      }
      sacc[s*64+qc] = a;
    }
    __syncthreads();
    if (tid < 64){
      float s=0.f;
      #pragma unroll
      for (int u=0;u<8;u++) s += sacc[u*64+tid];
      qv[tid] = s + b2f(qb1c[tid]);
    }
    __syncthreads();
    { // scores own l-quarter: l-pairs x 4 q-chunks of 16
      const int lp = tid & 127, qh = tid >> 7;
      float a0=0.f,a1=0.f;
      const unsigned short* kp = keyT + (size_t)n*65536 + (size_t)qh*16*1024 + p*256 + 2*lp;
      #pragma unroll 8
      for (int q=0;q<16;q++){
        ushort2 w = *reinterpret_cast<const ushort2*>(kp + (size_t)q*1024);
        float qq = qv[qh*16+q];
        a0 += qq*b2f(w.x); a1 += qq*b2f(w.y);
      }
      sacc[qh*256+2*lp]=a0; sacc[qh*256+2*lp+1]=a1;
    }
    __syncthreads();
    // wave-shuffle softmax partials
    float pmax, psum;
    {
      float s = -1e30f;
      if (tid < 256){
        s = sacc[tid]+sacc[256+tid]+sacc[512+tid]+sacc[768+tid];
        if (p*256+tid >= slen) s = -1e30f;
      }
      float m = s;
      #pragma unroll
      for (int off=32; off; off>>=1) m = fmaxf(m, __shfl_xor(m, off));
      if ((tid&63)==0) red[tid>>6] = m;
      __syncthreads();
      pmax = fmaxf(fmaxf(red[0],red[1]),fmaxf(red[2],red[3]));
      float e = 0.f;
      if (tid < 256){
        e = (p*256+tid < slen) ? __expf(s - pmax) : 0.f;
        earr[tid] = e;
      }
      float ss = e;
      #pragma unroll
      for (int off=32; off; off>>=1) ss += __shfl_xor(ss, off);
      if ((tid&63)==0) red[8+(tid>>6)] = ss;
      __syncthreads();
      psum = red[8]+red[9]+red[10]+red[11];
    }
    { // partial ctx from LDS value: h-pairs x 4 l-chunks of 64
      const int hp = tid & 127, lq = tid >> 7;
      float a0=0.f,a1=0.f;
      const unsigned short* vp = vlds + (size_t)(lq*64)*256 + 2*hp;
      #pragma unroll 8
      for (int l=0;l<64;l++){
        ushort2 w = *reinterpret_cast<const ushort2*>(vp + (size_t)l*256);
        float e = earr[lq*64+l];
        a0 += e*b2f(w.x); a1 += e*b2f(w.y);
      }
      sacc[lq*256+2*hp]=a0; sacc[lq*256+2*hp+1]=a1;
    }
    __syncthreads();
    if (tid < 256){
      float v = sacc[tid]+sacc[256+tid]+sacc[512+tid]+sacc[768+tid];
      pcl[tid] = v;
      ast64(PCw + p*256 + tid, pk(v, tag));
    }
    if (tid == 0){ ast64(STw + p*2, pk(pmax, tag)); ast64(STw + p*2 + 1, pk(psum, tag)); }
    // stats gather (all 4 parts): own from registers, remote by poll
    if (tid < 8){
      int q = tid >> 1, ix = tid & 1; float v;
      if (q == p) v = ix ? psum : pmax;
      else { const ull* w = STw + q*2 + ix; ull u = ald64(w);
             while ((unsigned)(u>>32) != tag) u = ald64(w);
             v = upk(u); }
      statl[tid] = v;
    }
    __syncthreads();
    if (tid == 0){
      float m0=statl[0], s0=statl[1], m1=statl[2], s1=statl[3];
      float m2=statl[4], s2=statl[5], m3=statl[6], s3=statl[7];
      float M = fmaxf(fmaxf(m0,m1),fmaxf(m2,m3));
      float w0=__expf(m0-M), w1=__expf(m1-M), w2=__expf(m2-M), w3=__expf(m3-M);
      float inv = 1.f/(s0*w0+s1*w1+s2*w2+s3*w3);
      wf[0]=w0*inv; wf[1]=w1*inv; wf[2]=w2*inv; wf[3]=w3*inv;
    }
    __syncthreads();
    if (tid < 256){
      // parallel remote polls: issue all 3 loads before checking any tag
      const int q0=(p+1)&3, q1=(p+2)&3, q2=(p+3)&3;
      const ull* w0 = PCw + q0*256 + tid;
      const ull* w1 = PCw + q1*256 + tid;
      const ull* w2 = PCw + q2*256 + tid;
      ull u0=ald64(w0), u1=ald64(w1), u2=ald64(w2);
      while ((unsigned)(u0>>32) != tag) u0 = ald64(w0);
      while ((unsigned)(u1>>32) != tag) u1 = ald64(w1);
      while ((unsigned)(u2>>32) != tag) u2 = ald64(w2);
      float acc = pcl[tid]*wf[p] + upk(u0)*wf[q0] + upk(u1)*wf[q1] + upk(u2)*wf[q2];
      ctx[tid] = acc;
      inc[tid] = acc;            // stage-A x-half
      inc[256+tid] = h0[tid];    // stage-A h-half (h0 from stage-B writeback)
    }
    __syncthreads();
  };

  attn(1);   // initial prev_ctx from inith[2] (h2 local)

  int lab = i64 ? labels[2*n] : labels[n];
  for (int t=0;t<256;t++){
    const unsigned tb = 4*(unsigned)t;
    const float* ger = gep + ((size_t)p*34+lab)*256;
    // prefetch next label (latency spans the whole step)
    int lab_next = 0;
    if (t < 255) lab_next = i64 ? labels[2*((t+1)*64+n)] : labels[(t+1)*64+n];
    // stage A: inc = {ctx, h0_prev} (folded by attn); out-proj(t-1) overlapped
    lstm_lds(Wl0, bsum_p + p*256, ger, 0, H0w, tb+2, t-1);
    // stage B: x = h0_new (fused poll), h = h1_prev; h0[] updated
    lstm_poll(Wl1, bsum_p + 1024 + p*256, H0w, tb+2, h1, h0, 1, H1w, tb+3);
    // stage C: x = h1_new (fused poll), h = h2_prev; h1[] updated
    lstm_poll(Wl2, bsum_p + 2048 + p*256, H1w, tb+3, h2, h1, 2, H2w, tb+4);
    // h2 full for attn/out-proj
    gather_h2(tb+4);
    // stage D: attention (folds inc = {ctx_new, h0} for next stage A)
    attn(tb+5);
    lab = lab_next;
  }
  outproj(255);
}

extern "C" void kernel_launch(void* const* d_in, const int* in_sizes, int n_in,
                              void* d_out, int out_size, void* d_ws, size_t ws_size,
                              hipStream_t stream) {
  const void* seqs  = d_in[0];
  const int* seq_lens = (const int*)d_in[1];
  const int* labels   = (const int*)d_in[2];
  const void* emb   = d_in[3];
  const void* inith = d_in[4];
  const void* initc = d_in[5];
  const void* Wih0 = d_in[6];  const void* Whh0 = d_in[7];
  const void* bih0 = d_in[8];  const void* bhh0 = d_in[9];
  const void* Wih1 = d_in[10]; const void* Whh1 = d_in[11];
  const void* bih1 = d_in[12]; const void* bhh1 = d_in[13];
  const void* Wih2 = d_in[14]; const void* Whh2 = d_in[15];
  const void* bih2 = d_in[16]; const void* bhh2 = d_in[17];
  const void* qW0 = d_in[18];  const void* qb0 = d_in[19];
  const void* qW1 = d_in[20];  const void* qb1 = d_in[21];
  const void* kW0 = d_in[22];  const void* kb0 = d_in[23];
  const void* kW1 = d_in[24];  const void* kb1 = d_in[25];
  const void* vW0 = d_in[26];  const void* vb0 = d_in[27];
  const void* vW1 = d_in[28];  const void* vb1 = d_in[29];
  const void* outW = d_in[30]; const void* outb = d_in[31];

  char* ws = (char*)d_ws;
  unsigned short* keyT  = (unsigned short*)(ws);             //  8,388,608 B  [64][64][1024]
  unsigned short* value = (unsigned short*)(ws + 8388608);   // 33,554,432 B  [64][1024][256]
  unsigned short* Wl0   = (unsigned short*)(ws + 41943040);  //  1,048,576 B  [4][512][256]
  unsigned short* Wl1   = (unsigned short*)(ws + 42991616);
  unsigned short* Wl2   = (unsigned short*)(ws + 44040192);
  unsigned short* kW0T  = (unsigned short*)(ws + 45088768);  //    524,288 B (prep-only)
  unsigned short* kW1T  = (unsigned short*)(ws + 45613056);  //     65,536 B (prep-only)
  unsigned short* vW0T  = (unsigned short*)(ws + 45678592);  //    262,144 B (prep-only)
  unsigned short* vW1T  = (unsigned short*)(ws + 45940736);  //    131,072 B (prep-only)
  unsigned short* qW0v  = (unsigned short*)(ws + 46071808);  //    131,072 B
  unsigned short* qW1v  = (unsigned short*)(ws + 46202880);  //     32,768 B
  float*          bsum  = (float*)(ws + 46235648);           //     12,288 B  [3][4][256]
  float*          gep   = (float*)(ws + 46247936);           //    139,264 B  [4][34][256]
  unsigned short* outWc = (unsigned short*)(ws + 46387200);  //     34,816 B
  unsigned short* inithc= (unsigned short*)(ws + 46422016);  //      1,536 B
  unsigned short* initcc= (unsigned short*)(ws + 46423552);  //      1,536 B
  unsigned short* qb0c  = (unsigned short*)(ws + 46425088);  //        512 B
  unsigned short* qb1c  = (unsigned short*)(ws + 46425600);  //        128 B
  unsigned short* outbc = (unsigned short*)(ws + 46425728);  //        128 B
  int*            dflags= (int*)(ws + 46425856);             //         16 B
  // tagged mailbox overlaps kW0T..vW1T (all consumed before speller starts):
  ull* hbw = (ull*)(ws + 45088768);                          //    921,600 B  [64][1800] ull

  sniff<<<dim3(1), dim3(64), 0, stream>>>(seqs, seq_lens, dflags);
  prep_transpose<<<dim3(8472), dim3(256), 0, stream>>>(
      Wih0,Whh0,Wih1,Whh1,Wih2,Whh2, kW0,kW1,vW0,vW1,qW0,qW1,
      bih0,bhh0,bih1,bhh1,bih2,bhh2,
      outW,inith,initc,qb0,qb1,outb, dflags,
      Wl0,Wl1,Wl2,kW0T,kW1T,vW0T,vW1T,qW0v,qW1v,bsum,
      outWc,inithc,initcc,qb0c,qb1c,outbc);
  prep_ge<<<dim3(34), dim3(256), 0, stream>>>(emb, Wih0, dflags, gep);
  key_mlp<<<dim3(4096), dim3(256), 0, stream>>>(seqs, kW0T, kb0, kW1T, kb1, dflags, keyT);
  value_mlp<<<dim3(4096), dim3(256), 0, stream>>>(seqs, vW0T, vb0, vW1T, vb1, dflags, value);
  zero_hbuf<<<dim3(450), dim3(256), 0, stream>>>(hbw);
  hipFuncSetAttribute((const void*)speller, hipFuncAttributeMaxDynamicSharedMemorySize, 131072);
  speller<<<dim3(256), dim3(512), 131072, stream>>>(
      keyT, value, Wl0, Wl1, Wl2, qW0v, qW1v, bsum, gep,
      inithc, initcc, qb0c, qb1c, outWc, outbc, labels, seq_lens, dflags,
      hbw, d_out);
}